// Round 3
// baseline (257.535 us; speedup 1.0000x reference)
//
#include <hip/hip_runtime.h>
#include <cstdint>

#define B_ 2
#define S_ 2048
#define D_ 1024
#define H_ 16
#define DK_ 64

typedef float f32x4 __attribute__((ext_vector_type(4)));
typedef __bf16 bf16x8 __attribute__((ext_vector_type(8)));
typedef unsigned short u16x8 __attribute__((ext_vector_type(8)));
typedef unsigned short u16x4 __attribute__((ext_vector_type(4)));

__device__ __forceinline__ unsigned short f2bf(float x) {
  unsigned int u = __builtin_bit_cast(unsigned int, x);
  u += 0x7FFFu + ((u >> 16) & 1u);   // round-to-nearest-even
  return (unsigned short)(u >> 16);
}

__device__ __forceinline__ void gload16(const void* g, void* l) {
  __builtin_amdgcn_global_load_lds((__attribute__((address_space(1))) void*)(void*)g,
                                   (__attribute__((address_space(3))) void*)l, 16, 0, 0);
}

// ---------------- fp32 -> bf16 convert (q,k,v fused via grid.z) ----------------
__global__ __launch_bounds__(256) void cvt3_kernel(const float* __restrict__ q,
                                                   const float* __restrict__ k,
                                                   const float* __restrict__ v,
                                                   unsigned short* __restrict__ oq,
                                                   unsigned short* __restrict__ ok,
                                                   unsigned short* __restrict__ ov, int n) {
  const float* in = blockIdx.z == 0 ? q : blockIdx.z == 1 ? k : v;
  unsigned short* out = blockIdx.z == 0 ? oq : blockIdx.z == 1 ? ok : ov;
  int idx = blockIdx.x * blockDim.x + threadIdx.x;
  int stride = gridDim.x * blockDim.x;
  for (int i = idx * 4; i < n; i += stride * 4) {
    f32x4 vv = *(const f32x4*)(in + i);
    u16x4 o;
#pragma unroll
    for (int j = 0; j < 4; ++j) o[j] = f2bf(vv[j]);
    *(u16x4*)(out + i) = o;
  }
}

// ---------------- weight transpose + convert: WT[n][k] = W[k][n] ----------------
__global__ __launch_bounds__(256) void wtrans_kernel(const float* __restrict__ w0, const float* __restrict__ w1,
                                                     const float* __restrict__ w2, const float* __restrict__ w3,
                                                     unsigned short* o0, unsigned short* o1,
                                                     unsigned short* o2, unsigned short* o3) {
  const float* W;
  unsigned short* O;
  if (blockIdx.z == 0) { W = w0; O = o0; }
  else if (blockIdx.z == 1) { W = w1; O = o1; }
  else if (blockIdx.z == 2) { W = w2; O = o2; }
  else { W = w3; O = o3; }
  __shared__ float t[32][33];
  int n0 = blockIdx.x * 32, k0 = blockIdx.y * 32;
  int tx = threadIdx.x, ty = threadIdx.y;  // block (32,8)
  for (int i = ty; i < 32; i += 8) t[i][tx] = W[(size_t)(k0 + i) * D_ + n0 + tx];
  __syncthreads();
  for (int i = ty; i < 32; i += 8) O[(size_t)(n0 + i) * D_ + k0 + tx] = f2bf(t[tx][i]);
}

// ---------------- mask bit-pack: mb bit i <-> mask flat element i ----------------
// Each block: 4 waves x 64 lanes = 256 elements. Grid must be B*S*S/256.
__global__ __launch_bounds__(256) void maskpack_kernel(const int* __restrict__ mask,
                                                       unsigned int* __restrict__ mb) {
  int wid = (blockIdx.x << 2) + (threadIdx.x >> 6);
  int lane = threadIdx.x & 63;
  size_t base = (size_t)wid << 6;
  unsigned long long bits = __ballot(mask[base + lane] != 0);
  if (lane == 0) *(unsigned long long*)(mb + (base >> 5)) = bits;
}

// ---------------- 128x128 bf16 GEMM, B transposed (BT[n][k]), bias add ----------------
// MODE: 0 = bf16 row-major out, 1 = f32 row-major out, 2 = bf16 transposed out to [B][D][S]
template <int MODE>
__device__ __forceinline__ void gemm128(const unsigned short* __restrict__ A,
                                        const unsigned short* __restrict__ BT,
                                        const float* __restrict__ bias,
                                        void* __restrict__ Cp, int M, int N, int K) {
  __shared__ unsigned short Al[128 * 32];
  __shared__ unsigned short Bl[128 * 32];
  const int tid = threadIdx.x;
  const int lane = tid & 63;
  const int w = tid >> 6;
  const int wr = w >> 1, wc = w & 1;
  const int m0 = blockIdx.y * 128, n0 = blockIdx.x * 128;

  f32x4 acc[4][4] = {};
  const int nk = K / 32;
  const int srow = lane >> 2;        // 0..15 within 16-row chunk
  const int scol = (lane & 3) * 8;   // ushort offset within 32-col row

  const int fr = lane & 15;
  const int fc = (lane >> 4) * 8;

  for (int kt = 0; kt < nk; ++kt) {
    __syncthreads();
#pragma unroll
    for (int it = 0; it < 2; ++it) {
      int chunk = it * 4 + w;
      const unsigned short* ga = A + (size_t)(m0 + chunk * 16 + srow) * K + kt * 32 + scol;
      gload16(ga, &Al[chunk * 512]);
      const unsigned short* gb = BT + (size_t)(n0 + chunk * 16 + srow) * K + kt * 32 + scol;
      gload16(gb, &Bl[chunk * 512]);
    }
    __syncthreads();
    bf16x8 af[4], bf[4];
#pragma unroll
    for (int i = 0; i < 4; ++i)
      af[i] = __builtin_bit_cast(bf16x8, *(const u16x8*)&Al[(wr * 64 + i * 16 + fr) * 32 + fc]);
#pragma unroll
    for (int j = 0; j < 4; ++j)
      bf[j] = __builtin_bit_cast(bf16x8, *(const u16x8*)&Bl[(wc * 64 + j * 16 + fr) * 32 + fc]);
#pragma unroll
    for (int i = 0; i < 4; ++i)
#pragma unroll
      for (int j = 0; j < 4; ++j)
        acc[i][j] = __builtin_amdgcn_mfma_f32_16x16x32_bf16(af[i], bf[j], acc[i][j], 0, 0, 0);
  }

  const int rg = (lane >> 4) * 4;
  const int cg = lane & 15;
#pragma unroll
  for (int i = 0; i < 4; ++i)
#pragma unroll
    for (int j = 0; j < 4; ++j) {
      int col = n0 + wc * 64 + j * 16 + cg;
      float bv = bias[col];
#pragma unroll
      for (int e = 0; e < 4; ++e) {
        int row = m0 + wr * 64 + i * 16 + rg + e;
        float v = acc[i][j][e] + bv;
        if (MODE == 1)
          ((float*)Cp)[(size_t)row * N + col] = v;
        else if (MODE == 0)
          ((unsigned short*)Cp)[(size_t)row * N + col] = f2bf(v);
        else  // V^T layout: [b][d][s], b = row>>11, s = row&2047, d = col
          ((unsigned short*)Cp)[((size_t)(row >> 11) * D_ + col) * S_ + (row & (S_ - 1))] = f2bf(v);
      }
    }
}

__global__ __launch_bounds__(256) void qkv_gemm_kernel(
    const unsigned short* __restrict__ xq, const unsigned short* __restrict__ xk,
    const unsigned short* __restrict__ xv, const unsigned short* __restrict__ wtq,
    const unsigned short* __restrict__ wtk, const unsigned short* __restrict__ wtv,
    const float* __restrict__ bq, const float* __restrict__ bk, const float* __restrict__ bv,
    unsigned short* q, unsigned short* k, unsigned short* vt) {
  if (blockIdx.z == 0)
    gemm128<0>(xq, wtq, bq, (void*)q, B_ * S_, D_, D_);
  else if (blockIdx.z == 1)
    gemm128<0>(xk, wtk, bk, (void*)k, B_ * S_, D_, D_);
  else
    gemm128<2>(xv, wtv, bv, (void*)vt, B_ * S_, D_, D_);
}

__global__ __launch_bounds__(256) void out_gemm_kernel(const unsigned short* __restrict__ x,
                                                       const unsigned short* __restrict__ wto,
                                                       const float* __restrict__ bo,
                                                       float* __restrict__ out) {
  gemm128<1>(x, wto, bo, (void*)out, B_ * S_, D_, D_);
}

// ---------------- flash attention ----------------
// Q,K bf16 [B,S,D] head-interleaved; Vt bf16 [B,D,S]; mb bit-packed mask; X out [B,S,D].
__global__ __launch_bounds__(256) void attn_kernel(const unsigned short* __restrict__ Q,
                                                   const unsigned short* __restrict__ K,
                                                   const unsigned short* __restrict__ Vt,
                                                   const unsigned int* __restrict__ mb,
                                                   unsigned short* __restrict__ X) {
  __shared__ unsigned short Kl[64 * 64];   // [kr][d], XOR-swizzled 16B chunks
  __shared__ unsigned short Vl[64 * 64];   // [d][kr], XOR-swizzled 16B chunks
  __shared__ unsigned short Pl[4][16 * 64];  // per-wave P tile, XOR-swizzled

  const int tid = threadIdx.x;
  const int lane = tid & 63;
  const int w = tid >> 6;
  const int qt = blockIdx.x;
  const int bh = blockIdx.y;
  const int b = bh >> 4, h = bh & 15;

  const size_t base = ((size_t)b * S_) * D_ + h * DK_;
  const size_t vtbase = ((size_t)b * D_ + h * DK_) * S_;
  const int q0 = qt * 64 + w * 16;

  const int fr = lane & 15;
  const int fc = (lane >> 4) * 8;
  const int drow = (lane >> 4) * 4;
  const int dcol = lane & 15;

  // Q fragments (d-chunks 0..31, 32..63)
  bf16x8 qf[2];
  {
    const unsigned short* qp = Q + base + (size_t)(q0 + fr) * D_;
    qf[0] = __builtin_bit_cast(bf16x8, *(const u16x8*)(qp + fc));
    qf[1] = __builtin_bit_cast(bf16x8, *(const u16x8*)(qp + 32 + fc));
  }

  f32x4 acc[4] = {};
  float mst[4], lst[4];
#pragma unroll
  for (int e = 0; e < 4; ++e) { mst[e] = -1e30f; lst[e] = 0.f; }

  // staging: lane l loads row l>>3, pre-swizzled seg (l&7)^(l>>3) so that the
  // LINEAR global_load_lds dest yields the XOR-swizzled LDS layout.
  const int lr = lane >> 3;
  const int seg = (lane & 7) ^ lr;
  const size_t mbase = ((size_t)b * S_ + q0 + drow) * 64;

  for (int kt = 0; kt < S_ / 64; ++kt) {
    __syncthreads();
#pragma unroll
    for (int c = 0; c < 2; ++c) {
      int r = w * 16 + c * 8 + lr;  // tile-local row; r&7 == lr
      gload16(K + base + (size_t)(kt * 64 + r) * D_ + seg * 8, &Kl[(w * 16 + c * 8) * 64]);
      gload16(Vt + vtbase + (size_t)r * S_ + kt * 64 + seg * 8, &Vl[(w * 16 + c * 8) * 64]);
    }
    // mask rows for this tile (issued early, L2-resident 1MB)
    unsigned long long mrow[4];
#pragma unroll
    for (int e = 0; e < 4; ++e)
      mrow[e] = *(const unsigned long long*)(mb + mbase + (size_t)e * 64 + kt * 2);
    __syncthreads();

    // scores: 4 key col-tiles of 16
    f32x4 sc[4];
#pragma unroll
    for (int kc = 0; kc < 4; ++kc) {
      int krow = kc * 16 + fr;
      int kb0 = (krow * 128 + fc * 2) ^ ((krow & 7) << 4);
      int kb1 = (krow * 128 + 64 + fc * 2) ^ ((krow & 7) << 4);
      bf16x8 k0 = __builtin_bit_cast(bf16x8, *(const u16x8*)&Kl[kb0 >> 1]);
      bf16x8 k1 = __builtin_bit_cast(bf16x8, *(const u16x8*)&Kl[kb1 >> 1]);
      f32x4 s = {};
      s = __builtin_amdgcn_mfma_f32_16x16x32_bf16(qf[0], k0, s, 0, 0, 0);
      s = __builtin_amdgcn_mfma_f32_16x16x32_bf16(qf[1], k1, s, 0, 0, 0);
      sc[kc] = s;
    }
    // mask + scale via bit tests
#pragma unroll
    for (int kc = 0; kc < 4; ++kc)
#pragma unroll
      for (int e = 0; e < 4; ++e) {
        unsigned bit = (unsigned)(mrow[e] >> (kc * 16 + dcol)) & 1u;
        sc[kc][e] = bit ? sc[kc][e] * 0.125f : -1e9f;
      }

    // online softmax with deferred rescale (T13)
#pragma unroll
    for (int e = 0; e < 4; ++e) {
      float rm = fmaxf(fmaxf(sc[0][e], sc[1][e]), fmaxf(sc[2][e], sc[3][e]));
      rm = fmaxf(rm, __shfl_xor(rm, 1));
      rm = fmaxf(rm, __shfl_xor(rm, 2));
      rm = fmaxf(rm, __shfl_xor(rm, 4));
      rm = fmaxf(rm, __shfl_xor(rm, 8));
      if (rm > mst[e] + 2.5f) {  // uniform within 16-lane group
        float alpha = __expf(mst[e] - rm);
        mst[e] = rm;
        lst[e] *= alpha;
#pragma unroll
        for (int nt = 0; nt < 4; ++nt) acc[nt][e] *= alpha;
      }
      float rs = 0.f;
#pragma unroll
      for (int kc = 0; kc < 4; ++kc) {
        float p = __expf(sc[kc][e] - mst[e]);
        sc[kc][e] = p;
        rs += p;
      }
      rs += __shfl_xor(rs, 1);
      rs += __shfl_xor(rs, 2);
      rs += __shfl_xor(rs, 4);
      rs += __shfl_xor(rs, 8);
      lst[e] += rs;
    }

    // P -> bf16 -> per-wave LDS (swizzled). Same-wave producer/consumer: DS in-order.
    unsigned short* pw = &Pl[w][0];
#pragma unroll
    for (int kc = 0; kc < 4; ++kc)
#pragma unroll
      for (int e = 0; e < 4; ++e) {
        int row = drow + e, col = kc * 16 + dcol;
        int boff = (row * 128 + col * 2) ^ ((row & 7) << 4);
        pw[boff >> 1] = f2bf(sc[kc][e]);
      }

    // PV
#pragma unroll
    for (int c = 0; c < 2; ++c) {
      int pb = (fr * 128 + (c * 32 + fc) * 2) ^ ((fr & 7) << 4);
      bf16x8 pf = __builtin_bit_cast(bf16x8, *(const u16x8*)&pw[pb >> 1]);
#pragma unroll
      for (int nt = 0; nt < 4; ++nt) {
        int d = nt * 16 + fr;
        int vb_ = (d * 128 + (c * 32 + fc) * 2) ^ ((d & 7) << 4);
        bf16x8 vf = __builtin_bit_cast(bf16x8, *(const u16x8*)&Vl[vb_ >> 1]);
        acc[nt] = __builtin_amdgcn_mfma_f32_16x16x32_bf16(pf, vf, acc[nt], 0, 0, 0);
      }
    }
  }

  // epilogue: normalize and store
#pragma unroll
  for (int nt = 0; nt < 4; ++nt)
#pragma unroll
    for (int e = 0; e < 4; ++e) {
      int qrow_g = qt * 64 + w * 16 + drow + e;
      int col = h * DK_ + nt * 16 + dcol;
      X[((size_t)b * S_ + qrow_g) * D_ + col] = f2bf(acc[nt][e] / lst[e]);
    }
}

extern "C" void kernel_launch(void* const* d_in, const int* in_sizes, int n_in,
                              void* d_out, int out_size, void* d_ws, size_t ws_size,
                              hipStream_t stream) {
  const float* query = (const float*)d_in[0];
  const float* key = (const float*)d_in[1];
  const float* value = (const float*)d_in[2];
  const int* mask = (const int*)d_in[3];
  const float* Wq = (const float*)d_in[4];
  const float* bq = (const float*)d_in[5];
  const float* Wk = (const float*)d_in[6];
  const float* bk = (const float*)d_in[7];
  const float* Wv = (const float*)d_in[8];
  const float* bv = (const float*)d_in[9];
  const float* Wo = (const float*)d_in[10];
  const float* bo = (const float*)d_in[11];
  float* out = (float*)d_out;

  const size_t ACT = (size_t)B_ * S_ * D_;  // 4,194,304
  const size_t WSZ = (size_t)D_ * D_;
  unsigned short* ws = (unsigned short*)d_ws;
  unsigned short* xq = ws;                 // also reused as xb (attn out) after qkv_gemm
  unsigned short* xk = xq + ACT;
  unsigned short* xv = xk + ACT;
  unsigned short* wtq = xv + ACT;
  unsigned short* wtk = wtq + WSZ;
  unsigned short* wtv = wtk + WSZ;
  unsigned short* wto = wtv + WSZ;
  unsigned short* qb = wto + WSZ;
  unsigned short* kb = qb + ACT;
  unsigned short* vt = kb + ACT;
  unsigned int* mbp = (unsigned int*)(vt + ACT);  // 1MB bit-packed mask
  unsigned short* xb = xq;                        // alias: xq dead after qkv_gemm

  cvt3_kernel<<<dim3(2048, 1, 3), 256, 0, stream>>>(query, key, value, xq, xk, xv, (int)ACT);

  dim3 tb(32, 8), tg(D_ / 32, D_ / 32, 4);
  wtrans_kernel<<<tg, tb, 0, stream>>>(Wq, Wk, Wv, Wo, wtq, wtk, wtv, wto);

  // 256 mask elements per block -> B*S*S/256 blocks (R2 bug: was /1024, only 1/4 packed)
  maskpack_kernel<<<(B_ * S_ * S_) / 256, 256, 0, stream>>>(mask, mbp);

  dim3 gg(D_ / 128, (B_ * S_) / 128, 3);
  qkv_gemm_kernel<<<gg, 256, 0, stream>>>(xq, xk, xv, wtq, wtk, wtv, bq, bk, bv, qb, kb, vt);

  dim3 ag(S_ / 64, B_ * H_);
  attn_kernel<<<ag, 256, 0, stream>>>(qb, kb, vt, mbp, xb);

  dim3 og(D_ / 128, (B_ * S_) / 128, 1);
  out_gemm_kernel<<<og, 256, 0, stream>>>(xb, wto, bo, out);
}

// Round 4
// 176.398 us; speedup vs baseline: 1.4600x; 1.4600x over previous
//
#include <hip/hip_runtime.h>
#include <cstdint>

#define B_ 2
#define S_ 2048
#define D_ 1024
#define H_ 16
#define DK_ 64
// 0.125 (1/sqrt(DK)) * log2(e): folded into Wq/bq so softmax uses exp2 directly
#define SCALE_ 0.18033688011112042f

typedef float f32x4 __attribute__((ext_vector_type(4)));
typedef float f32x16 __attribute__((ext_vector_type(16)));
typedef __bf16 bf16x8 __attribute__((ext_vector_type(8)));
typedef unsigned short u16x8 __attribute__((ext_vector_type(8)));
typedef unsigned short u16x4 __attribute__((ext_vector_type(4)));
typedef unsigned int u32x4 __attribute__((ext_vector_type(4)));

__device__ __forceinline__ unsigned short f2bf(float x) {
  unsigned int u = __builtin_bit_cast(unsigned int, x);
  u += 0x7FFFu + ((u >> 16) & 1u);   // round-to-nearest-even
  return (unsigned short)(u >> 16);
}

__device__ __forceinline__ void gload16(const void* g, void* l) {
  __builtin_amdgcn_global_load_lds((__attribute__((address_space(1))) void*)(void*)g,
                                   (__attribute__((address_space(3))) void*)l, 16, 0, 0);
}

__device__ __forceinline__ float exp2v(float x) {
  float r;
  asm("v_exp_f32 %0, %1" : "=v"(r) : "v"(x));
  return r;
}

__device__ __forceinline__ unsigned int cvtpk(float a, float b) {
  unsigned int r;
  asm("v_cvt_pk_bf16_f32 %0, %1, %2" : "=v"(r) : "v"(a), "v"(b));
  return r;
}

// ---------------- fp32 -> bf16 convert (q,k,v fused via grid.z) ----------------
__global__ __launch_bounds__(256) void cvt3_kernel(const float* __restrict__ q,
                                                   const float* __restrict__ k,
                                                   const float* __restrict__ v,
                                                   unsigned short* __restrict__ oq,
                                                   unsigned short* __restrict__ ok,
                                                   unsigned short* __restrict__ ov, int n) {
  const float* in = blockIdx.z == 0 ? q : blockIdx.z == 1 ? k : v;
  unsigned short* out = blockIdx.z == 0 ? oq : blockIdx.z == 1 ? ok : ov;
  int idx = blockIdx.x * blockDim.x + threadIdx.x;
  int stride = gridDim.x * blockDim.x;
  for (int i = idx * 4; i < n; i += stride * 4) {
    f32x4 vv = *(const f32x4*)(in + i);
    u16x4 o;
#pragma unroll
    for (int j = 0; j < 4; ++j) o[j] = f2bf(vv[j]);
    *(u16x4*)(out + i) = o;
  }
}

// ---------------- weight transpose + convert: WT[n][k] = W[k][n] ----------------
// z==0 (Wq): scaled by SCALE_ so attention scores arrive pre-scaled for exp2.
__global__ __launch_bounds__(256) void wtrans_kernel(const float* __restrict__ w0, const float* __restrict__ w1,
                                                     const float* __restrict__ w2, const float* __restrict__ w3,
                                                     unsigned short* o0, unsigned short* o1,
                                                     unsigned short* o2, unsigned short* o3) {
  const float* W;
  unsigned short* O;
  float sc = 1.f;
  if (blockIdx.z == 0) { W = w0; O = o0; sc = SCALE_; }
  else if (blockIdx.z == 1) { W = w1; O = o1; }
  else if (blockIdx.z == 2) { W = w2; O = o2; }
  else { W = w3; O = o3; }
  __shared__ float t[32][33];
  int n0 = blockIdx.x * 32, k0 = blockIdx.y * 32;
  int tx = threadIdx.x, ty = threadIdx.y;  // block (32,8)
  for (int i = ty; i < 32; i += 8) t[i][tx] = W[(size_t)(k0 + i) * D_ + n0 + tx];
  __syncthreads();
  for (int i = ty; i < 32; i += 8) O[(size_t)(n0 + i) * D_ + k0 + tx] = f2bf(t[tx][i] * sc);
}

// ---------------- mask bit-pack: mb bit i <-> mask flat element i ----------------
// Each block: 4 waves x 64 lanes = 256 elements. Grid must be B*S*S/256.
__global__ __launch_bounds__(256) void maskpack_kernel(const int* __restrict__ mask,
                                                       unsigned int* __restrict__ mb) {
  int wid = (blockIdx.x << 2) + (threadIdx.x >> 6);
  int lane = threadIdx.x & 63;
  size_t base = (size_t)wid << 6;
  unsigned long long bits = __ballot(mask[base + lane] != 0);
  if (lane == 0) *(unsigned long long*)(mb + (base >> 5)) = bits;
}

// ---------------- 128x128 bf16 GEMM, B transposed (BT[n][k]), bias add ----------------
// MODE: 0 = bf16 row-major out, 1 = f32 row-major out, 2 = bf16 transposed out to [B][D][S]
template <int MODE>
__device__ __forceinline__ void gemm128(const unsigned short* __restrict__ A,
                                        const unsigned short* __restrict__ BT,
                                        const float* __restrict__ bias, float bsc,
                                        void* __restrict__ Cp, int M, int N, int K) {
  __shared__ unsigned short Al[128 * 32];
  __shared__ unsigned short Bl[128 * 32];
  const int tid = threadIdx.x;
  const int lane = tid & 63;
  const int w = tid >> 6;
  const int wr = w >> 1, wc = w & 1;
  const int m0 = blockIdx.y * 128, n0 = blockIdx.x * 128;

  f32x4 acc[4][4] = {};
  const int nk = K / 32;
  const int srow = lane >> 2;        // 0..15 within 16-row chunk
  const int scol = (lane & 3) * 8;   // ushort offset within 32-col row

  const int fr = lane & 15;
  const int fc = (lane >> 4) * 8;

  for (int kt = 0; kt < nk; ++kt) {
    __syncthreads();
#pragma unroll
    for (int it = 0; it < 2; ++it) {
      int chunk = it * 4 + w;
      const unsigned short* ga = A + (size_t)(m0 + chunk * 16 + srow) * K + kt * 32 + scol;
      gload16(ga, &Al[chunk * 512]);
      const unsigned short* gb = BT + (size_t)(n0 + chunk * 16 + srow) * K + kt * 32 + scol;
      gload16(gb, &Bl[chunk * 512]);
    }
    __syncthreads();
    bf16x8 af[4], bf[4];
#pragma unroll
    for (int i = 0; i < 4; ++i)
      af[i] = __builtin_bit_cast(bf16x8, *(const u16x8*)&Al[(wr * 64 + i * 16 + fr) * 32 + fc]);
#pragma unroll
    for (int j = 0; j < 4; ++j)
      bf[j] = __builtin_bit_cast(bf16x8, *(const u16x8*)&Bl[(wc * 64 + j * 16 + fr) * 32 + fc]);
#pragma unroll
    for (int i = 0; i < 4; ++i)
#pragma unroll
      for (int j = 0; j < 4; ++j)
        acc[i][j] = __builtin_amdgcn_mfma_f32_16x16x32_bf16(af[i], bf[j], acc[i][j], 0, 0, 0);
  }

  const int rg = (lane >> 4) * 4;
  const int cg = lane & 15;
#pragma unroll
  for (int i = 0; i < 4; ++i)
#pragma unroll
    for (int j = 0; j < 4; ++j) {
      int col = n0 + wc * 64 + j * 16 + cg;
      float bv = bias[col] * bsc;
#pragma unroll
      for (int e = 0; e < 4; ++e) {
        int row = m0 + wr * 64 + i * 16 + rg + e;
        float v = acc[i][j][e] + bv;
        if (MODE == 1)
          ((float*)Cp)[(size_t)row * N + col] = v;
        else if (MODE == 0)
          ((unsigned short*)Cp)[(size_t)row * N + col] = f2bf(v);
        else  // V^T layout: [b][d][s], b = row>>11, s = row&2047, d = col
          ((unsigned short*)Cp)[((size_t)(row >> 11) * D_ + col) * S_ + (row & (S_ - 1))] = f2bf(v);
      }
    }
}

__global__ __launch_bounds__(256) void qkv_gemm_kernel(
    const unsigned short* __restrict__ xq, const unsigned short* __restrict__ xk,
    const unsigned short* __restrict__ xv, const unsigned short* __restrict__ wtq,
    const unsigned short* __restrict__ wtk, const unsigned short* __restrict__ wtv,
    const float* __restrict__ bq, const float* __restrict__ bk, const float* __restrict__ bv,
    unsigned short* q, unsigned short* k, unsigned short* vt) {
  if (blockIdx.z == 0)
    gemm128<0>(xq, wtq, bq, SCALE_, (void*)q, B_ * S_, D_, D_);
  else if (blockIdx.z == 1)
    gemm128<0>(xk, wtk, bk, 1.f, (void*)k, B_ * S_, D_, D_);
  else
    gemm128<2>(xv, wtv, bv, 1.f, (void*)vt, B_ * S_, D_, D_);
}

__global__ __launch_bounds__(256) void out_gemm_kernel(const unsigned short* __restrict__ x,
                                                       const unsigned short* __restrict__ wto,
                                                       const float* __restrict__ bo,
                                                       float* __restrict__ out) {
  gemm128<1>(x, wto, bo, 1.f, (void*)out, B_ * S_, D_, D_);
}

// ---------------- flash attention, swapped-QK^T 32x32 in-register softmax ----------------
// Q,K bf16 [B,S,D] (Q pre-scaled by SCALE_); Vt bf16 [B,D,S]; mb bit-packed mask.
// 4 waves x 32 q-rows = 128 q/block; KVBLK=64; double-buffered LDS.
__global__ __launch_bounds__(256) void attn_kernel(const unsigned short* __restrict__ Q,
                                                   const unsigned short* __restrict__ K,
                                                   const unsigned short* __restrict__ Vt,
                                                   const unsigned int* __restrict__ mb,
                                                   unsigned short* __restrict__ X) {
  __shared__ unsigned short Kl[2][64 * 64];  // [kr][d], XOR-swizzled 16B chunks
  __shared__ unsigned short Vl[2][64 * 64];  // [d][kr], XOR-swizzled 16B chunks

  const int tid = threadIdx.x;
  const int lane = tid & 63;
  const int w = tid >> 6;
  const int ql = lane & 31;   // this lane's q-row within the wave
  const int hi = lane >> 5;
  const int qt = blockIdx.x;
  const int bh = blockIdx.y;
  const int b = bh >> 4, h = bh & 15;
  const int q_g = qt * 128 + w * 32 + ql;

  const size_t qkbase = ((size_t)b * S_) * D_ + h * DK_;
  const size_t vtbase = ((size_t)b * D_ + h * DK_) * S_;

  // Q as B-operand fragments: frag c holds Q[q_g][c*16 + hi*8 + j]
  bf16x8 qf[4];
  {
    const unsigned short* qp = Q + qkbase + (size_t)q_g * D_ + hi * 8;
#pragma unroll
    for (int c = 0; c < 4; ++c)
      qf[c] = __builtin_bit_cast(bf16x8, *(const u16x8*)(qp + c * 16));
  }

  // staging: lane l covers row lr=l>>3 of its 8-row chunk; pre-swizzled source seg
  const int lr = lane >> 3;
  const int sg = lane & 7;
  const int seg = sg ^ lr;
  const unsigned short* Ks = K + qkbase + (size_t)(w * 16 + lr) * D_ + seg * 8;
  const unsigned short* Vs = Vt + vtbase + (size_t)(w * 16 + lr) * S_ + seg * 8;

  auto stage = [&](int kt, int bufi) {
#pragma unroll
    for (int c = 0; c < 2; ++c) {
      gload16(Ks + ((size_t)kt * 64 + c * 8) * D_, &Kl[bufi][(w * 16 + c * 8) * 64]);
      gload16(Vs + (size_t)(c * 8) * S_ + kt * 64, &Vl[bufi][(w * 16 + c * 8) * 64]);
    }
  };

  const unsigned long long* mrow =
      (const unsigned long long*)mb + ((size_t)b * S_ + q_g) * 32;

  f32x16 o0 = {}, o1 = {};  // O^T accumulators, d-tiles 0 (d 0..31) and 1 (d 32..63)
  float lsum = 0.f;
  const float NINF = -__builtin_inff();
  const int sw = (ql & 7) << 4;  // read-side XOR (rows of both K and V^T tiles)

  stage(0, 0);

  for (int kt = 0; kt < S_ / 64; ++kt) {
    const int buf = kt & 1;
    __syncthreads();                  // drains stage(kt); prior reads of buf^1 done
    if (kt < S_ / 64 - 1) stage(kt + 1, buf ^ 1);
    unsigned long long M = mrow[kt];  // 64 mask bits for this lane's q-row

    // ---- QK^T: S^T[kr][q], two 32-row subtiles ----
    f32x16 s0 = {}, s1 = {};
    const char* Kb = (const char*)&Kl[buf][0];
#pragma unroll
    for (int c = 0; c < 4; ++c) {
      int col = c * 32 + hi * 16;
      bf16x8 k0 = __builtin_bit_cast(bf16x8, *(const u16x8*)(Kb + ((ql * 128 + col) ^ sw)));
      s0 = __builtin_amdgcn_mfma_f32_32x32x16_bf16(k0, qf[c], s0, 0, 0, 0);
      bf16x8 k1 = __builtin_bit_cast(bf16x8, *(const u16x8*)(Kb + (((32 + ql) * 128 + col) ^ sw)));
      s1 = __builtin_amdgcn_mfma_f32_32x32x16_bf16(k1, qf[c], s1, 0, 0, 0);
    }

    // ---- mask + exp2 (fixed base: no online max needed) ----
    unsigned int W0 = (unsigned int)(M >> (hi * 4));
    unsigned int W1 = (unsigned int)(M >> (32 + hi * 4));
    float rsA = 0.f, rsB = 0.f, rsC = 0.f, rsD = 0.f;
#pragma unroll
    for (int r = 0; r < 16; ++r) {
      const int krl = (r & 3) + 8 * (r >> 2);  // bit index after the hi*4 shift
      float v0 = ((W0 >> krl) & 1u) ? s0[r] : NINF;
      float p0 = exp2v(v0);
      s0[r] = p0;
      float v1 = ((W1 >> krl) & 1u) ? s1[r] : NINF;
      float p1 = exp2v(v1);
      s1[r] = p1;
      if (r & 1) { rsB += p0; rsD += p1; } else { rsA += p0; rsC += p1; }
    }
    lsum += (rsA + rsB) + (rsC + rsD);

    // ---- pack P -> bf16 B-fragments (cvt_pk + cross-half swap) ----
    u32x4 pw[4];
#pragma unroll
    for (int kc = 0; kc < 4; ++kc) {
      const int rb = (kc & 1) * 8;
      float pa0, pa1, pa2, pa3, pa4, pa5, pa6, pa7;
      if (kc < 2) {
        pa0 = s0[rb + 0]; pa1 = s0[rb + 1]; pa2 = s0[rb + 2]; pa3 = s0[rb + 3];
        pa4 = s0[rb + 4]; pa5 = s0[rb + 5]; pa6 = s0[rb + 6]; pa7 = s0[rb + 7];
      } else {
        pa0 = s1[rb + 0]; pa1 = s1[rb + 1]; pa2 = s1[rb + 2]; pa3 = s1[rb + 3];
        pa4 = s1[rb + 4]; pa5 = s1[rb + 5]; pa6 = s1[rb + 6]; pa7 = s1[rb + 7];
      }
      unsigned int w0 = cvtpk(pa0, pa1), w1 = cvtpk(pa2, pa3);
      unsigned int w2 = cvtpk(pa4, pa5), w3 = cvtpk(pa6, pa7);
      unsigned int u0, u1, u2, u3;
#if __has_builtin(__builtin_amdgcn_permlane32_swap)
      { auto r02 = __builtin_amdgcn_permlane32_swap(w0, w2, false, false);
        u0 = r02[0]; u2 = r02[1]; }
      { auto r13 = __builtin_amdgcn_permlane32_swap(w1, w3, false, false);
        u1 = r13[0]; u3 = r13[1]; }
#else
      { unsigned int t0 = (unsigned int)__shfl_xor((int)w0, 32);
        unsigned int t2 = (unsigned int)__shfl_xor((int)w2, 32);
        u0 = hi ? t2 : w0; u2 = hi ? w2 : t0;
        unsigned int t1 = (unsigned int)__shfl_xor((int)w1, 32);
        unsigned int t3 = (unsigned int)__shfl_xor((int)w3, 32);
        u1 = hi ? t3 : w1; u3 = hi ? w3 : t1; }
#endif
      pw[kc] = u32x4{u0, u1, u2, u3};
    }

    // ---- PV: O^T[d][q] += V^T[d][k] P^T[k][q] ----
    const char* Vb = (const char*)&Vl[buf][0];
#pragma unroll
    for (int kc = 0; kc < 4; ++kc) {
      bf16x8 pf = __builtin_bit_cast(bf16x8, pw[kc]);
      int col = kc * 32 + hi * 16;
      bf16x8 v0 = __builtin_bit_cast(bf16x8, *(const u16x8*)(Vb + ((ql * 128 + col) ^ sw)));
      o0 = __builtin_amdgcn_mfma_f32_32x32x16_bf16(v0, pf, o0, 0, 0, 0);
      bf16x8 v1 = __builtin_bit_cast(bf16x8, *(const u16x8*)(Vb + (((32 + ql) * 128 + col) ^ sw)));
      o1 = __builtin_amdgcn_mfma_f32_32x32x16_bf16(v1, pf, o1, 0, 0, 0);
    }
  }

  // ---- epilogue: combine lane pair, normalize, transposed packed stores ----
  lsum += __shfl_xor(lsum, 32);
  float inv = 1.f / lsum;
  unsigned short* Xp = X + ((size_t)b * S_ + q_g) * D_ + h * DK_;
#pragma unroll
  for (int rb = 0; rb < 4; ++rb) {
    int d0 = 8 * rb + 4 * hi;
    *(unsigned int*)(Xp + d0) = cvtpk(o0[4 * rb + 0] * inv, o0[4 * rb + 1] * inv);
    *(unsigned int*)(Xp + d0 + 2) = cvtpk(o0[4 * rb + 2] * inv, o0[4 * rb + 3] * inv);
    *(unsigned int*)(Xp + 32 + d0) = cvtpk(o1[4 * rb + 0] * inv, o1[4 * rb + 1] * inv);
    *(unsigned int*)(Xp + 32 + d0 + 2) = cvtpk(o1[4 * rb + 2] * inv, o1[4 * rb + 3] * inv);
  }
}

extern "C" void kernel_launch(void* const* d_in, const int* in_sizes, int n_in,
                              void* d_out, int out_size, void* d_ws, size_t ws_size,
                              hipStream_t stream) {
  const float* query = (const float*)d_in[0];
  const float* key = (const float*)d_in[1];
  const float* value = (const float*)d_in[2];
  const int* mask = (const int*)d_in[3];
  const float* Wq = (const float*)d_in[4];
  const float* bq = (const float*)d_in[5];
  const float* Wk = (const float*)d_in[6];
  const float* bk = (const float*)d_in[7];
  const float* Wv = (const float*)d_in[8];
  const float* bv = (const float*)d_in[9];
  const float* Wo = (const float*)d_in[10];
  const float* bo = (const float*)d_in[11];
  float* out = (float*)d_out;

  const size_t ACT = (size_t)B_ * S_ * D_;  // 4,194,304
  const size_t WSZ = (size_t)D_ * D_;
  unsigned short* ws = (unsigned short*)d_ws;
  unsigned short* xq = ws;                 // also reused as xb (attn out) after qkv_gemm
  unsigned short* xk = xq + ACT;
  unsigned short* xv = xk + ACT;
  unsigned short* wtq = xv + ACT;
  unsigned short* wtk = wtq + WSZ;
  unsigned short* wtv = wtk + WSZ;
  unsigned short* wto = wtv + WSZ;
  unsigned short* qb = wto + WSZ;
  unsigned short* kb = qb + ACT;
  unsigned short* vt = kb + ACT;
  unsigned int* mbp = (unsigned int*)(vt + ACT);  // 1MB bit-packed mask
  unsigned short* xb = xq;                        // alias: xq dead after qkv_gemm

  cvt3_kernel<<<dim3(2048, 1, 3), 256, 0, stream>>>(query, key, value, xq, xk, xv, (int)ACT);

  dim3 tb(32, 8), tg(D_ / 32, D_ / 32, 4);
  wtrans_kernel<<<tg, tb, 0, stream>>>(Wq, Wk, Wv, Wo, wtq, wtk, wtv, wto);

  maskpack_kernel<<<(B_ * S_ * S_) / 256, 256, 0, stream>>>(mask, mbp);

  dim3 gg(D_ / 128, (B_ * S_) / 128, 3);
  qkv_gemm_kernel<<<gg, 256, 0, stream>>>(xq, xk, xv, wtq, wtk, wtv, bq, bk, bv, qb, kb, vt);

  dim3 ag(S_ / 128, B_ * H_);
  attn_kernel<<<ag, 256, 0, stream>>>(qb, kb, vt, mbp, xb);

  dim3 og(D_ / 128, (B_ * S_) / 128, 1);
  out_gemm_kernel<<<og, 256, 0, stream>>>(xb, wto, bo, out);
}

// Round 5
// 171.964 us; speedup vs baseline: 1.4976x; 1.0258x over previous
//
#include <hip/hip_runtime.h>
#include <cstdint>

#define B_ 2
#define S_ 2048
#define D_ 1024
#define H_ 16
#define DK_ 64
// 0.125 (1/sqrt(DK)) * log2(e): folded into Wq/bq so softmax uses exp2 directly
#define SCALE_ 0.18033688011112042f

typedef float f32x4 __attribute__((ext_vector_type(4)));
typedef float f32x16 __attribute__((ext_vector_type(16)));
typedef __bf16 bf16x8 __attribute__((ext_vector_type(8)));
typedef unsigned short u16x8 __attribute__((ext_vector_type(8)));
typedef unsigned short u16x4 __attribute__((ext_vector_type(4)));
typedef unsigned int u32x4 __attribute__((ext_vector_type(4)));

__device__ __forceinline__ unsigned short f2bf(float x) {
  unsigned int u = __builtin_bit_cast(unsigned int, x);
  u += 0x7FFFu + ((u >> 16) & 1u);   // round-to-nearest-even
  return (unsigned short)(u >> 16);
}

__device__ __forceinline__ void gload16(const void* g, void* l) {
  __builtin_amdgcn_global_load_lds((__attribute__((address_space(1))) void*)(void*)g,
                                   (__attribute__((address_space(3))) void*)l, 16, 0, 0);
}

__device__ __forceinline__ float exp2v(float x) {
  float r;
  asm("v_exp_f32 %0, %1" : "=v"(r) : "v"(x));
  return r;
}

__device__ __forceinline__ unsigned int cvtpk(float a, float b) {
  unsigned int r;
  asm("v_cvt_pk_bf16_f32 %0, %1, %2" : "=v"(r) : "v"(a), "v"(b));
  return r;
}

// ---------------- fp32 -> bf16 convert (q,k,v fused via grid.z) ----------------
__global__ __launch_bounds__(256) void cvt3_kernel(const float* __restrict__ q,
                                                   const float* __restrict__ k,
                                                   const float* __restrict__ v,
                                                   unsigned short* __restrict__ oq,
                                                   unsigned short* __restrict__ ok,
                                                   unsigned short* __restrict__ ov, int n) {
  const float* in = blockIdx.z == 0 ? q : blockIdx.z == 1 ? k : v;
  unsigned short* out = blockIdx.z == 0 ? oq : blockIdx.z == 1 ? ok : ov;
  int idx = blockIdx.x * blockDim.x + threadIdx.x;
  int stride = gridDim.x * blockDim.x;
  for (int i = idx * 4; i < n; i += stride * 4) {
    f32x4 vv = *(const f32x4*)(in + i);
    u16x4 o;
#pragma unroll
    for (int j = 0; j < 4; ++j) o[j] = f2bf(vv[j]);
    *(u16x4*)(out + i) = o;
  }
}

// ---------------- weight transpose + convert: WT[n][k] = W[k][n] ----------------
// z==0 (Wq): scaled by SCALE_ so attention scores arrive pre-scaled for exp2.
__global__ __launch_bounds__(256) void wtrans_kernel(const float* __restrict__ w0, const float* __restrict__ w1,
                                                     const float* __restrict__ w2, const float* __restrict__ w3,
                                                     unsigned short* o0, unsigned short* o1,
                                                     unsigned short* o2, unsigned short* o3) {
  const float* W;
  unsigned short* O;
  float sc = 1.f;
  if (blockIdx.z == 0) { W = w0; O = o0; sc = SCALE_; }
  else if (blockIdx.z == 1) { W = w1; O = o1; }
  else if (blockIdx.z == 2) { W = w2; O = o2; }
  else { W = w3; O = o3; }
  __shared__ float t[32][33];
  int n0 = blockIdx.x * 32, k0 = blockIdx.y * 32;
  int tx = threadIdx.x, ty = threadIdx.y;  // block (32,8)
  for (int i = ty; i < 32; i += 8) t[i][tx] = W[(size_t)(k0 + i) * D_ + n0 + tx];
  __syncthreads();
  for (int i = ty; i < 32; i += 8) O[(size_t)(n0 + i) * D_ + k0 + tx] = f2bf(t[tx][i] * sc);
}

// ---------------- mask bit-pack: mb bit i <-> mask flat element i ----------------
// Each block: 4 waves x 64 lanes = 256 elements. Grid must be B*S*S/256.
__global__ __launch_bounds__(256) void maskpack_kernel(const int* __restrict__ mask,
                                                       unsigned int* __restrict__ mb) {
  int wid = (blockIdx.x << 2) + (threadIdx.x >> 6);
  int lane = threadIdx.x & 63;
  size_t base = (size_t)wid << 6;
  unsigned long long bits = __ballot(mask[base + lane] != 0);
  if (lane == 0) *(unsigned long long*)(mb + (base >> 5)) = bits;
}

// ---------------- 128x128 bf16 GEMM, B transposed (BT[n][k]), bias add ----------------
// MODE: 0 = bf16 row-major out, 1 = f32 row-major out, 2 = bf16 transposed out to [B][D][S]
template <int MODE>
__device__ __forceinline__ void gemm128(const unsigned short* __restrict__ A,
                                        const unsigned short* __restrict__ BT,
                                        const float* __restrict__ bias, float bsc,
                                        void* __restrict__ Cp, int M, int N, int K) {
  __shared__ unsigned short Al[128 * 32];
  __shared__ unsigned short Bl[128 * 32];
  const int tid = threadIdx.x;
  const int lane = tid & 63;
  const int w = tid >> 6;
  const int wr = w >> 1, wc = w & 1;
  const int m0 = blockIdx.y * 128, n0 = blockIdx.x * 128;

  f32x4 acc[4][4] = {};
  const int nk = K / 32;
  const int srow = lane >> 2;        // 0..15 within 16-row chunk
  const int scol = (lane & 3) * 8;   // ushort offset within 32-col row

  const int fr = lane & 15;
  const int fc = (lane >> 4) * 8;

  for (int kt = 0; kt < nk; ++kt) {
    __syncthreads();
#pragma unroll
    for (int it = 0; it < 2; ++it) {
      int chunk = it * 4 + w;
      const unsigned short* ga = A + (size_t)(m0 + chunk * 16 + srow) * K + kt * 32 + scol;
      gload16(ga, &Al[chunk * 512]);
      const unsigned short* gb = BT + (size_t)(n0 + chunk * 16 + srow) * K + kt * 32 + scol;
      gload16(gb, &Bl[chunk * 512]);
    }
    __syncthreads();
    bf16x8 af[4], bf[4];
#pragma unroll
    for (int i = 0; i < 4; ++i)
      af[i] = __builtin_bit_cast(bf16x8, *(const u16x8*)&Al[(wr * 64 + i * 16 + fr) * 32 + fc]);
#pragma unroll
    for (int j = 0; j < 4; ++j)
      bf[j] = __builtin_bit_cast(bf16x8, *(const u16x8*)&Bl[(wc * 64 + j * 16 + fr) * 32 + fc]);
#pragma unroll
    for (int i = 0; i < 4; ++i)
#pragma unroll
      for (int j = 0; j < 4; ++j)
        acc[i][j] = __builtin_amdgcn_mfma_f32_16x16x32_bf16(af[i], bf[j], acc[i][j], 0, 0, 0);
  }

  const int rg = (lane >> 4) * 4;
  const int cg = lane & 15;
#pragma unroll
  for (int i = 0; i < 4; ++i)
#pragma unroll
    for (int j = 0; j < 4; ++j) {
      int col = n0 + wc * 64 + j * 16 + cg;
      float bv = bias[col] * bsc;
#pragma unroll
      for (int e = 0; e < 4; ++e) {
        int row = m0 + wr * 64 + i * 16 + rg + e;
        float v = acc[i][j][e] + bv;
        if (MODE == 1)
          ((float*)Cp)[(size_t)row * N + col] = v;
        else if (MODE == 0)
          ((unsigned short*)Cp)[(size_t)row * N + col] = f2bf(v);
        else  // V^T layout: [b][d][s], b = row>>11, s = row&2047, d = col
          ((unsigned short*)Cp)[((size_t)(row >> 11) * D_ + col) * S_ + (row & (S_ - 1))] = f2bf(v);
      }
    }
}

__global__ __launch_bounds__(256) void qkv_gemm_kernel(
    const unsigned short* __restrict__ xq, const unsigned short* __restrict__ xk,
    const unsigned short* __restrict__ xv, const unsigned short* __restrict__ wtq,
    const unsigned short* __restrict__ wtk, const unsigned short* __restrict__ wtv,
    const float* __restrict__ bq, const float* __restrict__ bk, const float* __restrict__ bv,
    unsigned short* q, unsigned short* k, unsigned short* vt) {
  if (blockIdx.z == 0)
    gemm128<0>(xq, wtq, bq, SCALE_, (void*)q, B_ * S_, D_, D_);
  else if (blockIdx.z == 1)
    gemm128<0>(xk, wtk, bk, 1.f, (void*)k, B_ * S_, D_, D_);
  else
    gemm128<2>(xv, wtv, bv, 1.f, (void*)vt, B_ * S_, D_, D_);
}

__global__ __launch_bounds__(256) void out_gemm_kernel(const unsigned short* __restrict__ x,
                                                       const unsigned short* __restrict__ wto,
                                                       const float* __restrict__ bo,
                                                       float* __restrict__ out) {
  gemm128<1>(x, wto, bo, 1.f, (void*)out, B_ * S_, D_, D_);
}

// ---------------- flash attention, swapped-QK^T 32x32 in-register softmax ----------------
// Q,K bf16 [B,S,D] (Q pre-scaled by SCALE_); Vt bf16 [B,D,S]; mb bit-packed mask.
// 4 waves x 32 q-rows = 128 q/block; KVBLK=64; double-buffered LDS.
__global__ __launch_bounds__(256) void attn_kernel(const unsigned short* __restrict__ Q,
                                                   const unsigned short* __restrict__ K,
                                                   const unsigned short* __restrict__ Vt,
                                                   const unsigned int* __restrict__ mb,
                                                   unsigned short* __restrict__ X) {
  __shared__ unsigned short Kl[2][64 * 64];  // [kr][d], XOR-swizzled 16B chunks
  __shared__ unsigned short Vl[2][64 * 64];  // [d][kr], XOR-swizzled 16B chunks

  const int tid = threadIdx.x;
  const int lane = tid & 63;
  const int w = tid >> 6;
  const int ql = lane & 31;   // this lane's q-row within the wave
  const int hi = lane >> 5;

  // XCD-bijective remap: 512 blocks = 8 XCDs x 64; each XCD owns 4 consecutive bh
  // (2MB K/V working set, L2-resident).
  const int wg = blockIdx.x + gridDim.x * blockIdx.y;
  const int swz = (wg & 7) * 64 + (wg >> 3);
  const int qt = swz & 15;
  const int bh = swz >> 4;
  const int b = bh >> 4, h = bh & 15;
  const int q_g = qt * 128 + w * 32 + ql;

  const size_t qkbase = ((size_t)b * S_) * D_ + h * DK_;
  const size_t vtbase = ((size_t)b * D_ + h * DK_) * S_;

  // Q as B-operand fragments: frag c holds Q[q_g][c*16 + hi*8 + j]
  bf16x8 qf[4];
  {
    const unsigned short* qp = Q + qkbase + (size_t)q_g * D_ + hi * 8;
#pragma unroll
    for (int c = 0; c < 4; ++c)
      qf[c] = __builtin_bit_cast(bf16x8, *(const u16x8*)(qp + c * 16));
  }

  // staging: lane l covers row lr=l>>3 of its 8-row chunk; pre-swizzled source seg
  const int lr = lane >> 3;
  const int sg = lane & 7;
  const int seg = sg ^ lr;
  const unsigned short* Ks = K + qkbase + (size_t)(w * 16 + lr) * D_ + seg * 8;
  const unsigned short* Vs = Vt + vtbase + (size_t)(w * 16 + lr) * S_ + seg * 8;

  auto stage = [&](int kt, int bufi) {
#pragma unroll
    for (int c = 0; c < 2; ++c) {
      gload16(Ks + ((size_t)kt * 64 + c * 8) * D_, &Kl[bufi][(w * 16 + c * 8) * 64]);
      gload16(Vs + (size_t)(c * 8) * S_ + kt * 64, &Vl[bufi][(w * 16 + c * 8) * 64]);
    }
  };

  const unsigned long long* mrow =
      (const unsigned long long*)mb + ((size_t)b * S_ + q_g) * 32;

  f32x16 o0 = {}, o1 = {};  // O^T accumulators, d-tiles 0 (d 0..31) and 1 (d 32..63)
  f32x16 o2 = {};           // ones-MFMA accumulator: every row = sum_k P (lsum)
  const int sw = (ql & 7) << 4;  // read-side XOR (rows of both K and V^T tiles)

  const unsigned int one2 = 0x3F803F80u;  // two bf16 1.0
  const bf16x8 onesf = __builtin_bit_cast(bf16x8, u32x4{one2, one2, one2, one2});

  stage(0, 0);
  unsigned long long Mnext = mrow[0];

  for (int kt = 0; kt < S_ / 64; ++kt) {
    const int buf = kt & 1;
    __syncthreads();                  // drains stage(kt); prior reads of buf^1 done
    if (kt < S_ / 64 - 1) stage(kt + 1, buf ^ 1);
    unsigned long long M = Mnext;
    if (kt < S_ / 64 - 1) Mnext = mrow[kt + 1];  // prefetch next tile's mask bits

    // ---- QK^T: S^T[kr][q], two 32-row subtiles ----
    f32x16 s0 = {}, s1 = {};
    const char* Kb = (const char*)&Kl[buf][0];
#pragma unroll
    for (int c = 0; c < 4; ++c) {
      int col = c * 32 + hi * 16;
      bf16x8 k0 = __builtin_bit_cast(bf16x8, *(const u16x8*)(Kb + ((ql * 128 + col) ^ sw)));
      s0 = __builtin_amdgcn_mfma_f32_32x32x16_bf16(k0, qf[c], s0, 0, 0, 0);
      bf16x8 k1 = __builtin_bit_cast(bf16x8, *(const u16x8*)(Kb + (((32 + ql) * 128 + col) ^ sw)));
      s1 = __builtin_amdgcn_mfma_f32_32x32x16_bf16(k1, qf[c], s1, 0, 0, 0);
    }

    // ---- exp2 then AND-mask (bfe_i32 -> all-ones/zero word; masked P = 0) ----
    unsigned int W0 = (unsigned int)(M >> (hi * 4));
    unsigned int W1 = (unsigned int)(M >> (32 + hi * 4));
#pragma unroll
    for (int r = 0; r < 16; ++r) {
      const int krl = (r & 3) + 8 * (r >> 2);  // bit index after the hi*4 shift
      unsigned int mk0 = (unsigned int)((int)(W0 << (31 - krl)) >> 31);
      float p0 = exp2v(s0[r]);
      s0[r] = __builtin_bit_cast(float, __builtin_bit_cast(unsigned int, p0) & mk0);
      unsigned int mk1 = (unsigned int)((int)(W1 << (31 - krl)) >> 31);
      float p1 = exp2v(s1[r]);
      s1[r] = __builtin_bit_cast(float, __builtin_bit_cast(unsigned int, p1) & mk1);
    }

    // ---- pack P -> bf16 B-fragments (cvt_pk + cross-half swap) ----
    u32x4 pw[4];
#pragma unroll
    for (int kc = 0; kc < 4; ++kc) {
      const int rb = (kc & 1) * 8;
      float pa0, pa1, pa2, pa3, pa4, pa5, pa6, pa7;
      if (kc < 2) {
        pa0 = s0[rb + 0]; pa1 = s0[rb + 1]; pa2 = s0[rb + 2]; pa3 = s0[rb + 3];
        pa4 = s0[rb + 4]; pa5 = s0[rb + 5]; pa6 = s0[rb + 6]; pa7 = s0[rb + 7];
      } else {
        pa0 = s1[rb + 0]; pa1 = s1[rb + 1]; pa2 = s1[rb + 2]; pa3 = s1[rb + 3];
        pa4 = s1[rb + 4]; pa5 = s1[rb + 5]; pa6 = s1[rb + 6]; pa7 = s1[rb + 7];
      }
      unsigned int w0 = cvtpk(pa0, pa1), w1 = cvtpk(pa2, pa3);
      unsigned int w2 = cvtpk(pa4, pa5), w3 = cvtpk(pa6, pa7);
      unsigned int u0, u1, u2, u3;
#if __has_builtin(__builtin_amdgcn_permlane32_swap)
      { auto r02 = __builtin_amdgcn_permlane32_swap(w0, w2, false, false);
        u0 = r02[0]; u2 = r02[1]; }
      { auto r13 = __builtin_amdgcn_permlane32_swap(w1, w3, false, false);
        u1 = r13[0]; u3 = r13[1]; }
#else
      { unsigned int t0 = (unsigned int)__shfl_xor((int)w0, 32);
        unsigned int t2 = (unsigned int)__shfl_xor((int)w2, 32);
        u0 = hi ? t2 : w0; u2 = hi ? w2 : t0;
        unsigned int t1 = (unsigned int)__shfl_xor((int)w1, 32);
        unsigned int t3 = (unsigned int)__shfl_xor((int)w3, 32);
        u1 = hi ? t3 : w1; u3 = hi ? w3 : t1; }
#endif
      pw[kc] = u32x4{u0, u1, u2, u3};
    }

    // ---- PV: O^T[d][q] += V^T[d][k] P^T[k][q]; o2 += ones*P (lsum on MFMA pipe) ----
    const char* Vb = (const char*)&Vl[buf][0];
#pragma unroll
    for (int kc = 0; kc < 4; ++kc) {
      bf16x8 pf = __builtin_bit_cast(bf16x8, pw[kc]);
      int col = kc * 32 + hi * 16;
      bf16x8 v0 = __builtin_bit_cast(bf16x8, *(const u16x8*)(Vb + ((ql * 128 + col) ^ sw)));
      o0 = __builtin_amdgcn_mfma_f32_32x32x16_bf16(v0, pf, o0, 0, 0, 0);
      bf16x8 v1 = __builtin_bit_cast(bf16x8, *(const u16x8*)(Vb + (((32 + ql) * 128 + col) ^ sw)));
      o1 = __builtin_amdgcn_mfma_f32_32x32x16_bf16(v1, pf, o1, 0, 0, 0);
      o2 = __builtin_amdgcn_mfma_f32_32x32x16_bf16(onesf, pf, o2, 0, 0, 0);
    }
  }

  // ---- epilogue: normalize (lsum = o2[0], identical in all lanes of col ql) ----
  float inv = 1.f / o2[0];
  unsigned short* Xp = X + ((size_t)b * S_ + q_g) * D_ + h * DK_;
#pragma unroll
  for (int rb = 0; rb < 4; ++rb) {
    int d0 = 8 * rb + 4 * hi;
    *(unsigned int*)(Xp + d0) = cvtpk(o0[4 * rb + 0] * inv, o0[4 * rb + 1] * inv);
    *(unsigned int*)(Xp + d0 + 2) = cvtpk(o0[4 * rb + 2] * inv, o0[4 * rb + 3] * inv);
    *(unsigned int*)(Xp + 32 + d0) = cvtpk(o1[4 * rb + 0] * inv, o1[4 * rb + 1] * inv);
    *(unsigned int*)(Xp + 32 + d0 + 2) = cvtpk(o1[4 * rb + 2] * inv, o1[4 * rb + 3] * inv);
  }
}

extern "C" void kernel_launch(void* const* d_in, const int* in_sizes, int n_in,
                              void* d_out, int out_size, void* d_ws, size_t ws_size,
                              hipStream_t stream) {
  const float* query = (const float*)d_in[0];
  const float* key = (const float*)d_in[1];
  const float* value = (const float*)d_in[2];
  const int* mask = (const int*)d_in[3];
  const float* Wq = (const float*)d_in[4];
  const float* bq = (const float*)d_in[5];
  const float* Wk = (const float*)d_in[6];
  const float* bk = (const float*)d_in[7];
  const float* Wv = (const float*)d_in[8];
  const float* bv = (const float*)d_in[9];
  const float* Wo = (const float*)d_in[10];
  const float* bo = (const float*)d_in[11];
  float* out = (float*)d_out;

  const size_t ACT = (size_t)B_ * S_ * D_;  // 4,194,304
  const size_t WSZ = (size_t)D_ * D_;
  unsigned short* ws = (unsigned short*)d_ws;
  unsigned short* xq = ws;                 // also reused as xb (attn out) after qkv_gemm
  unsigned short* xk = xq + ACT;
  unsigned short* xv = xk + ACT;
  unsigned short* wtq = xv + ACT;
  unsigned short* wtk = wtq + WSZ;
  unsigned short* wtv = wtk + WSZ;
  unsigned short* wto = wtv + WSZ;
  unsigned short* qb = wto + WSZ;
  unsigned short* kb = qb + ACT;
  unsigned short* vt = kb + ACT;
  unsigned int* mbp = (unsigned int*)(vt + ACT);  // 1MB bit-packed mask
  unsigned short* xb = xq;                        // alias: xq dead after qkv_gemm

  cvt3_kernel<<<dim3(2048, 1, 3), 256, 0, stream>>>(query, key, value, xq, xk, xv, (int)ACT);

  dim3 tb(32, 8), tg(D_ / 32, D_ / 32, 4);
  wtrans_kernel<<<tg, tb, 0, stream>>>(Wq, Wk, Wv, Wo, wtq, wtk, wtv, wto);

  maskpack_kernel<<<(B_ * S_ * S_) / 256, 256, 0, stream>>>(mask, mbp);

  dim3 gg(D_ / 128, (B_ * S_) / 128, 3);
  qkv_gemm_kernel<<<gg, 256, 0, stream>>>(xq, xk, xv, wtq, wtk, wtv, bq, bk, bv, qb, kb, vt);

  dim3 ag(S_ / 128, B_ * H_);
  attn_kernel<<<ag, 256, 0, stream>>>(qb, kb, vt, mbp, xb);

  dim3 og(D_ / 128, (B_ * S_) / 128, 1);
  out_gemm_kernel<<<og, 256, 0, stream>>>(xb, wto, bo, out);
}

// Round 6
// 169.376 us; speedup vs baseline: 1.5205x; 1.0153x over previous
//
#include <hip/hip_runtime.h>
#include <cstdint>

#define B_ 2
#define S_ 2048
#define D_ 1024
#define H_ 16
#define DK_ 64
// 0.125 (1/sqrt(DK)) * log2(e): folded into Wq/bq so softmax uses exp2 directly
#define SCALE_ 0.18033688011112042f

typedef float f32x4 __attribute__((ext_vector_type(4)));
typedef float f32x16 __attribute__((ext_vector_type(16)));
typedef __bf16 bf16x8 __attribute__((ext_vector_type(8)));
typedef unsigned short u16x8 __attribute__((ext_vector_type(8)));
typedef unsigned short u16x4 __attribute__((ext_vector_type(4)));
typedef unsigned int u32x4 __attribute__((ext_vector_type(4)));

__device__ __forceinline__ unsigned short f2bf(float x) {
  unsigned int u = __builtin_bit_cast(unsigned int, x);
  u += 0x7FFFu + ((u >> 16) & 1u);   // round-to-nearest-even
  return (unsigned short)(u >> 16);
}

__device__ __forceinline__ void gload16(const void* g, void* l) {
  __builtin_amdgcn_global_load_lds((__attribute__((address_space(1))) void*)(void*)g,
                                   (__attribute__((address_space(3))) void*)l, 16, 0, 0);
}

__device__ __forceinline__ float exp2v(float x) {
  float r;
  asm("v_exp_f32 %0, %1" : "=v"(r) : "v"(x));
  return r;
}

__device__ __forceinline__ unsigned int cvtpk(float a, float b) {
  unsigned int r;
  asm("v_cvt_pk_bf16_f32 %0, %1, %2" : "=v"(r) : "v"(a), "v"(b));
  return r;
}

// sign-extended 1-bit field: 0 or 0xFFFFFFFF
__device__ __forceinline__ unsigned int bit_mask(unsigned int w, int bit) {
#if __has_builtin(__builtin_amdgcn_sbfe)
  return (unsigned int)__builtin_amdgcn_sbfe((int)w, bit, 1);
#else
  return (unsigned int)((int)(w << (31 - bit)) >> 31);
#endif
}

// ---------------- fused prep: cvt3 | wtrans | maskpack ----------------
// blocks [0,6144): fp32->bf16 convert of q/k/v (2048 each)
// blocks [6144,10240): weight transpose+convert (1024 each of 4 weights)
// blocks [10240,43008): mask bit-pack (256 elements per block)
__global__ __launch_bounds__(256) void prep_kernel(
    const float* __restrict__ q, const float* __restrict__ k, const float* __restrict__ v,
    unsigned short* __restrict__ oq, unsigned short* __restrict__ ok,
    unsigned short* __restrict__ ov,
    const float* __restrict__ w0, const float* __restrict__ w1,
    const float* __restrict__ w2, const float* __restrict__ w3,
    unsigned short* o0, unsigned short* o1, unsigned short* o2, unsigned short* o3,
    const int* __restrict__ mask, unsigned int* __restrict__ mb) {
  __shared__ float t[32][33];
  const int bid = blockIdx.x;
  const int tid = threadIdx.x;
  if (bid < 6144) {
    const int z = bid >> 11, vb = bid & 2047;
    const float* in = z == 0 ? q : z == 1 ? k : v;
    unsigned short* out = z == 0 ? oq : z == 1 ? ok : ov;
    const int n = B_ * S_ * D_;
    int idx = vb * 256 + tid;
#pragma unroll
    for (int i = idx * 4; i < n; i += 2048 * 256 * 4) {
      f32x4 vv = *(const f32x4*)(in + i);
      u16x4 o;
#pragma unroll
      for (int j = 0; j < 4; ++j) o[j] = f2bf(vv[j]);
      *(u16x4*)(out + i) = o;
    }
  } else if (bid < 10240) {
    const int r = bid - 6144;
    const int z = r >> 10, rr = r & 1023;
    const float* W;
    unsigned short* O;
    float sc = 1.f;
    if (z == 0) { W = w0; O = o0; sc = SCALE_; }
    else if (z == 1) { W = w1; O = o1; }
    else if (z == 2) { W = w2; O = o2; }
    else { W = w3; O = o3; }
    const int n0 = (rr & 31) * 32, k0 = (rr >> 5) * 32;
    const int tx = tid & 31, ty = tid >> 5;
    for (int i = ty; i < 32; i += 8) t[i][tx] = W[(size_t)(k0 + i) * D_ + n0 + tx];
    __syncthreads();
    for (int i = ty; i < 32; i += 8) O[(size_t)(n0 + i) * D_ + k0 + tx] = f2bf(t[tx][i] * sc);
  } else {
    const int wid = ((bid - 10240) << 2) + (tid >> 6);
    const int lane = tid & 63;
    size_t base = (size_t)wid << 6;
    unsigned long long bits = __ballot(mask[base + lane] != 0);
    if (lane == 0) *(unsigned long long*)(mb + (base >> 5)) = bits;
  }
}

// ---------------- 128x128 bf16 GEMM, B transposed (BT[n][k]), bias add ----------------
// MODE: 0 = bf16 row-major out, 1 = f32 row-major out, 2 = bf16 transposed out to [B][D][S]
// Grid remapped XCD-chunked: nwg per slice must be 256 (8 n-blocks x 32 m-blocks).
template <int MODE>
__device__ __forceinline__ void gemm128(const unsigned short* __restrict__ A,
                                        const unsigned short* __restrict__ BT,
                                        const float* __restrict__ bias, float bsc,
                                        void* __restrict__ Cp, int M, int N, int K) {
  __shared__ unsigned short Al[128 * 32];
  __shared__ unsigned short Bl[128 * 32];
  const int tid = threadIdx.x;
  const int lane = tid & 63;
  const int w = tid >> 6;
  const int wr = w >> 1, wc = w & 1;
  // XCD-chunked bijective remap: XCD x gets 32 consecutive work items
  // (4 A-panels, 1MB + full B panel 2MB -> L2-resident per XCD).
  const int wg = blockIdx.x + gridDim.x * blockIdx.y;
  const int work = (wg & 7) * 32 + (wg >> 3);
  const int nx = N >> 7;
  const int m0 = (work / nx) * 128, n0 = (work % nx) * 128;

  f32x4 acc[4][4] = {};
  const int nk = K / 32;
  const int srow = lane >> 2;        // 0..15 within 16-row chunk
  const int scol = (lane & 3) * 8;   // ushort offset within 32-col row

  const int fr = lane & 15;
  const int fc = (lane >> 4) * 8;

  for (int kt = 0; kt < nk; ++kt) {
    __syncthreads();
#pragma unroll
    for (int it = 0; it < 2; ++it) {
      int chunk = it * 4 + w;
      const unsigned short* ga = A + (size_t)(m0 + chunk * 16 + srow) * K + kt * 32 + scol;
      gload16(ga, &Al[chunk * 512]);
      const unsigned short* gb = BT + (size_t)(n0 + chunk * 16 + srow) * K + kt * 32 + scol;
      gload16(gb, &Bl[chunk * 512]);
    }
    __syncthreads();
    bf16x8 af[4], bf[4];
#pragma unroll
    for (int i = 0; i < 4; ++i)
      af[i] = __builtin_bit_cast(bf16x8, *(const u16x8*)&Al[(wr * 64 + i * 16 + fr) * 32 + fc]);
#pragma unroll
    for (int j = 0; j < 4; ++j)
      bf[j] = __builtin_bit_cast(bf16x8, *(const u16x8*)&Bl[(wc * 64 + j * 16 + fr) * 32 + fc]);
    __builtin_amdgcn_s_setprio(1);
#pragma unroll
    for (int i = 0; i < 4; ++i)
#pragma unroll
      for (int j = 0; j < 4; ++j)
        acc[i][j] = __builtin_amdgcn_mfma_f32_16x16x32_bf16(af[i], bf[j], acc[i][j], 0, 0, 0);
    __builtin_amdgcn_s_setprio(0);
  }

  const int rg = (lane >> 4) * 4;
  const int cg = lane & 15;
#pragma unroll
  for (int i = 0; i < 4; ++i)
#pragma unroll
    for (int j = 0; j < 4; ++j) {
      int col = n0 + wc * 64 + j * 16 + cg;
      float bv = bias[col] * bsc;
#pragma unroll
      for (int e = 0; e < 4; ++e) {
        int row = m0 + wr * 64 + i * 16 + rg + e;
        float v = acc[i][j][e] + bv;
        if (MODE == 1)
          ((float*)Cp)[(size_t)row * N + col] = v;
        else if (MODE == 0)
          ((unsigned short*)Cp)[(size_t)row * N + col] = f2bf(v);
        else  // V^T layout: [b][d][s], b = row>>11, s = row&2047, d = col
          ((unsigned short*)Cp)[((size_t)(row >> 11) * D_ + col) * S_ + (row & (S_ - 1))] = f2bf(v);
      }
    }
}

__global__ __launch_bounds__(256) void qkv_gemm_kernel(
    const unsigned short* __restrict__ xq, const unsigned short* __restrict__ xk,
    const unsigned short* __restrict__ xv, const unsigned short* __restrict__ wtq,
    const unsigned short* __restrict__ wtk, const unsigned short* __restrict__ wtv,
    const float* __restrict__ bq, const float* __restrict__ bk, const float* __restrict__ bv,
    unsigned short* q, unsigned short* k, unsigned short* vt) {
  if (blockIdx.z == 0)
    gemm128<0>(xq, wtq, bq, SCALE_, (void*)q, B_ * S_, D_, D_);
  else if (blockIdx.z == 1)
    gemm128<0>(xk, wtk, bk, 1.f, (void*)k, B_ * S_, D_, D_);
  else
    gemm128<2>(xv, wtv, bv, 1.f, (void*)vt, B_ * S_, D_, D_);
}

__global__ __launch_bounds__(256) void out_gemm_kernel(const unsigned short* __restrict__ x,
                                                       const unsigned short* __restrict__ wto,
                                                       const float* __restrict__ bo,
                                                       float* __restrict__ out) {
  gemm128<1>(x, wto, bo, 1.f, (void*)out, B_ * S_, D_, D_);
}

// ---------------- flash attention, swapped-QK^T 32x32 in-register softmax ----------------
// Q,K bf16 [B,S,D] (Q pre-scaled by SCALE_); Vt bf16 [B,D,S]; mb bit-packed mask.
// 4 waves x 32 q-rows = 128 q/block; KVBLK=128 staged (2x64 compute halves);
// double-buffered 64KB LDS; 16 barrier iterations.
__global__ __launch_bounds__(256) void attn_kernel(const unsigned short* __restrict__ Q,
                                                   const unsigned short* __restrict__ K,
                                                   const unsigned short* __restrict__ Vt,
                                                   const unsigned int* __restrict__ mb,
                                                   unsigned short* __restrict__ X) {
  __shared__ unsigned short Kl[2][128 * 64];     // [kv 0..127][d], XOR-swizzled 16B chunks
  __shared__ unsigned short Vl[2][2][64 * 64];   // [half][d][kv 64], XOR-swizzled

  const int tid = threadIdx.x;
  const int lane = tid & 63;
  const int w = tid >> 6;
  const int ql = lane & 31;   // this lane's q-row within the wave
  const int hi = lane >> 5;

  // XCD-bijective remap: 512 blocks = 8 XCDs x 64; each XCD owns 4 consecutive bh
  const int wg = blockIdx.x + gridDim.x * blockIdx.y;
  const int swz = (wg & 7) * 64 + (wg >> 3);
  const int qt = swz & 15;
  const int bh = swz >> 4;
  const int b = bh >> 4, h = bh & 15;
  const int q_g = qt * 128 + w * 32 + ql;

  const size_t qkbase = ((size_t)b * S_) * D_ + h * DK_;
  const size_t vtbase = ((size_t)b * D_ + h * DK_) * S_;

  // Q as B-operand fragments: frag c holds Q[q_g][c*16 + hi*8 + j]
  bf16x8 qf[4];
  {
    const unsigned short* qp = Q + qkbase + (size_t)q_g * D_ + hi * 8;
#pragma unroll
    for (int c = 0; c < 4; ++c)
      qf[c] = __builtin_bit_cast(bf16x8, *(const u16x8*)(qp + c * 16));
  }

  // staging: lane l covers row lr=l>>3 of its 8-row chunk; pre-swizzled source seg
  const int lr = lane >> 3;
  const int seg = (lane & 7) ^ lr;
  const unsigned short* Ks = K + qkbase + (size_t)(w * 32 + lr) * D_ + seg * 8;
  const unsigned short* Vs = Vt + vtbase + (size_t)(w * 16 + lr) * S_ + seg * 8;

  auto stage = [&](int kt, int bufi) {  // kt indexes 128-row KV tiles
#pragma unroll
    for (int c = 0; c < 4; ++c)
      gload16(Ks + ((size_t)kt * 128 + c * 8) * D_, &Kl[bufi][(w * 32 + c * 8) * 64]);
#pragma unroll
    for (int c = 0; c < 4; ++c)
      gload16(Vs + (size_t)((c & 1) * 8) * S_ + kt * 128 + (c >> 1) * 64,
              &Vl[bufi][c >> 1][(w * 16 + (c & 1) * 8) * 64]);
  };

  const unsigned long long* mrow =
      (const unsigned long long*)mb + ((size_t)b * S_ + q_g) * 32;

  f32x16 o0 = {}, o1 = {};  // O^T accumulators, d-tiles 0 (d 0..31) and 1 (d 32..63)
  f32x16 o2 = {};           // ones-MFMA accumulator: every row = sum_k P (lsum)
  const int sw = (ql & 7) << 4;  // read-side XOR (rows of both K and V^T tiles)

  const unsigned int one2 = 0x3F803F80u;  // two bf16 1.0
  const bf16x8 onesf = __builtin_bit_cast(bf16x8, u32x4{one2, one2, one2, one2});

  stage(0, 0);
  const int NT = S_ / 128;

  for (int kt = 0; kt < NT; ++kt) {
    const int buf = kt & 1;
    __syncthreads();                  // drains stage(kt); prior reads of buf^1 done
    if (kt < NT - 1) stage(kt + 1, buf ^ 1);
    // mask words for both halves (L2-resident; issued early)
    unsigned long long M0 = mrow[kt * 2], M1 = mrow[kt * 2 + 1];

#pragma unroll
    for (int hh = 0; hh < 2; ++hh) {
      const unsigned long long M = hh ? M1 : M0;
      const char* Kb = (const char*)&Kl[buf][hh * 64 * 64];

      // ---- QK^T: S^T[kr][q], two 32-row subtiles ----
      f32x16 s0 = {}, s1 = {};
      __builtin_amdgcn_s_setprio(1);
#pragma unroll
      for (int c = 0; c < 4; ++c) {
        int col = c * 32 + hi * 16;
        bf16x8 k0 = __builtin_bit_cast(bf16x8, *(const u16x8*)(Kb + ((ql * 128 + col) ^ sw)));
        s0 = __builtin_amdgcn_mfma_f32_32x32x16_bf16(k0, qf[c], s0, 0, 0, 0);
        bf16x8 k1 = __builtin_bit_cast(bf16x8, *(const u16x8*)(Kb + (((32 + ql) * 128 + col) ^ sw)));
        s1 = __builtin_amdgcn_mfma_f32_32x32x16_bf16(k1, qf[c], s1, 0, 0, 0);
      }
      __builtin_amdgcn_s_setprio(0);

      // ---- exp2 then AND-mask (sbfe -> all-ones/zero word; masked P = 0) ----
      unsigned int W0 = (unsigned int)(M >> (hi * 4));
      unsigned int W1 = (unsigned int)(M >> (32 + hi * 4));
#pragma unroll
      for (int r = 0; r < 16; ++r) {
        const int krl = (r & 3) + 8 * (r >> 2);  // bit index after the hi*4 shift
        unsigned int mk0 = bit_mask(W0, krl);
        float p0 = exp2v(s0[r]);
        s0[r] = __builtin_bit_cast(float, __builtin_bit_cast(unsigned int, p0) & mk0);
        unsigned int mk1 = bit_mask(W1, krl);
        float p1 = exp2v(s1[r]);
        s1[r] = __builtin_bit_cast(float, __builtin_bit_cast(unsigned int, p1) & mk1);
      }

      // ---- pack P -> bf16 B-fragments (cvt_pk + cross-half swap) ----
      u32x4 pw[4];
#pragma unroll
      for (int kc = 0; kc < 4; ++kc) {
        const int rb = (kc & 1) * 8;
        float pa0, pa1, pa2, pa3, pa4, pa5, pa6, pa7;
        if (kc < 2) {
          pa0 = s0[rb + 0]; pa1 = s0[rb + 1]; pa2 = s0[rb + 2]; pa3 = s0[rb + 3];
          pa4 = s0[rb + 4]; pa5 = s0[rb + 5]; pa6 = s0[rb + 6]; pa7 = s0[rb + 7];
        } else {
          pa0 = s1[rb + 0]; pa1 = s1[rb + 1]; pa2 = s1[rb + 2]; pa3 = s1[rb + 3];
          pa4 = s1[rb + 4]; pa5 = s1[rb + 5]; pa6 = s1[rb + 6]; pa7 = s1[rb + 7];
        }
        unsigned int w0 = cvtpk(pa0, pa1), w1 = cvtpk(pa2, pa3);
        unsigned int w2 = cvtpk(pa4, pa5), w3 = cvtpk(pa6, pa7);
        unsigned int u0, u1, u2, u3;
#if __has_builtin(__builtin_amdgcn_permlane32_swap)
        { auto r02 = __builtin_amdgcn_permlane32_swap(w0, w2, false, false);
          u0 = r02[0]; u2 = r02[1]; }
        { auto r13 = __builtin_amdgcn_permlane32_swap(w1, w3, false, false);
          u1 = r13[0]; u3 = r13[1]; }
#else
        { unsigned int t0 = (unsigned int)__shfl_xor((int)w0, 32);
          unsigned int t2 = (unsigned int)__shfl_xor((int)w2, 32);
          u0 = hi ? t2 : w0; u2 = hi ? w2 : t0;
          unsigned int t1 = (unsigned int)__shfl_xor((int)w1, 32);
          unsigned int t3 = (unsigned int)__shfl_xor((int)w3, 32);
          u1 = hi ? t3 : w1; u3 = hi ? w3 : t1; }
#endif
        pw[kc] = u32x4{u0, u1, u2, u3};
      }

      // ---- PV: O^T[d][q] += V^T[d][k] P^T[k][q]; o2 += ones*P (lsum on MFMA pipe) ----
      const char* Vb = (const char*)&Vl[buf][hh][0];
      __builtin_amdgcn_s_setprio(1);
#pragma unroll
      for (int kc = 0; kc < 4; ++kc) {
        bf16x8 pf = __builtin_bit_cast(bf16x8, pw[kc]);
        int col = kc * 32 + hi * 16;
        bf16x8 v0 = __builtin_bit_cast(bf16x8, *(const u16x8*)(Vb + ((ql * 128 + col) ^ sw)));
        o0 = __builtin_amdgcn_mfma_f32_32x32x16_bf16(v0, pf, o0, 0, 0, 0);
        bf16x8 v1 = __builtin_bit_cast(bf16x8, *(const u16x8*)(Vb + (((32 + ql) * 128 + col) ^ sw)));
        o1 = __builtin_amdgcn_mfma_f32_32x32x16_bf16(v1, pf, o1, 0, 0, 0);
        o2 = __builtin_amdgcn_mfma_f32_32x32x16_bf16(onesf, pf, o2, 0, 0, 0);
      }
      __builtin_amdgcn_s_setprio(0);
    }
  }

  // ---- epilogue: normalize (lsum = o2[0], identical in all lanes of col ql) ----
  float inv = 1.f / o2[0];
  unsigned short* Xp = X + ((size_t)b * S_ + q_g) * D_ + h * DK_;
#pragma unroll
  for (int rb = 0; rb < 4; ++rb) {
    int d0 = 8 * rb + 4 * hi;
    *(unsigned int*)(Xp + d0) = cvtpk(o0[4 * rb + 0] * inv, o0[4 * rb + 1] * inv);
    *(unsigned int*)(Xp + d0 + 2) = cvtpk(o0[4 * rb + 2] * inv, o0[4 * rb + 3] * inv);
    *(unsigned int*)(Xp + 32 + d0) = cvtpk(o1[4 * rb + 0] * inv, o1[4 * rb + 1] * inv);
    *(unsigned int*)(Xp + 32 + d0 + 2) = cvtpk(o1[4 * rb + 2] * inv, o1[4 * rb + 3] * inv);
  }
}

extern "C" void kernel_launch(void* const* d_in, const int* in_sizes, int n_in,
                              void* d_out, int out_size, void* d_ws, size_t ws_size,
                              hipStream_t stream) {
  const float* query = (const float*)d_in[0];
  const float* key = (const float*)d_in[1];
  const float* value = (const float*)d_in[2];
  const int* mask = (const int*)d_in[3];
  const float* Wq = (const float*)d_in[4];
  const float* bq = (const float*)d_in[5];
  const float* Wk = (const float*)d_in[6];
  const float* bk = (const float*)d_in[7];
  const float* Wv = (const float*)d_in[8];
  const float* bv = (const float*)d_in[9];
  const float* Wo = (const float*)d_in[10];
  const float* bo = (const float*)d_in[11];
  float* out = (float*)d_out;

  const size_t ACT = (size_t)B_ * S_ * D_;  // 4,194,304
  const size_t WSZ = (size_t)D_ * D_;
  unsigned short* ws = (unsigned short*)d_ws;
  unsigned short* xq = ws;                 // also reused as xb (attn out) after qkv_gemm
  unsigned short* xk = xq + ACT;
  unsigned short* xv = xk + ACT;
  unsigned short* wtq = xv + ACT;
  unsigned short* wtk = wtq + WSZ;
  unsigned short* wtv = wtk + WSZ;
  unsigned short* wto = wtv + WSZ;
  unsigned short* qb = wto + WSZ;
  unsigned short* kb = qb + ACT;
  unsigned short* vt = kb + ACT;
  unsigned int* mbp = (unsigned int*)(vt + ACT);  // 1MB bit-packed mask
  unsigned short* xb = xq;                        // alias: xq dead after qkv_gemm

  prep_kernel<<<43008, 256, 0, stream>>>(query, key, value, xq, xk, xv,
                                         Wq, Wk, Wv, Wo, wtq, wtk, wtv, wto,
                                         mask, mbp);

  dim3 gg(8, 32, 3);
  qkv_gemm_kernel<<<gg, 256, 0, stream>>>(xq, xk, xv, wtq, wtk, wtv, bq, bk, bv, qb, kb, vt);

  dim3 ag(S_ / 128, B_ * H_);
  attn_kernel<<<ag, 256, 0, stream>>>(qb, kb, vt, mbp, xb);

  dim3 og(8, 32, 1);
  out_gemm_kernel<<<og, 256, 0, stream>>>(xb, wto, bo, out);
}

// Round 7
// 163.569 us; speedup vs baseline: 1.5745x; 1.0355x over previous
//
#include <hip/hip_runtime.h>
#include <cstdint>

#define B_ 2
#define S_ 2048
#define D_ 1024
#define H_ 16
#define DK_ 64
// 0.125 (1/sqrt(DK)) * log2(e): folded into Wq/bq so softmax uses exp2 directly
#define SCALE_ 0.18033688011112042f

typedef float f32x4 __attribute__((ext_vector_type(4)));
typedef float f32x16 __attribute__((ext_vector_type(16)));
typedef __bf16 bf16x8 __attribute__((ext_vector_type(8)));
typedef unsigned short u16x8 __attribute__((ext_vector_type(8)));
typedef unsigned short u16x4 __attribute__((ext_vector_type(4)));
typedef unsigned int u32x4 __attribute__((ext_vector_type(4)));

__device__ __forceinline__ unsigned short f2bf(float x) {
  unsigned int u = __builtin_bit_cast(unsigned int, x);
  u += 0x7FFFu + ((u >> 16) & 1u);   // round-to-nearest-even
  return (unsigned short)(u >> 16);
}

__device__ __forceinline__ void gload16(const void* g, void* l) {
  __builtin_amdgcn_global_load_lds((__attribute__((address_space(1))) void*)(void*)g,
                                   (__attribute__((address_space(3))) void*)l, 16, 0, 0);
}

__device__ __forceinline__ float exp2v(float x) {
  float r;
  asm("v_exp_f32 %0, %1" : "=v"(r) : "v"(x));
  return r;
}

__device__ __forceinline__ unsigned int cvtpk(float a, float b) {
  unsigned int r;
  asm("v_cvt_pk_bf16_f32 %0, %1, %2" : "=v"(r) : "v"(a), "v"(b));
  return r;
}

// sign-extended 1-bit field: 0 or 0xFFFFFFFF
__device__ __forceinline__ unsigned int bit_mask(unsigned int w, int bit) {
#if __has_builtin(__builtin_amdgcn_sbfe)
  return (unsigned int)__builtin_amdgcn_sbfe((int)w, bit, 1);
#else
  return (unsigned int)((int)(w << (31 - bit)) >> 31);
#endif
}

// ---------------- fused prep: cvt3 | wtrans | maskpack ----------------
__global__ __launch_bounds__(256) void prep_kernel(
    const float* __restrict__ q, const float* __restrict__ k, const float* __restrict__ v,
    unsigned short* __restrict__ oq, unsigned short* __restrict__ ok,
    unsigned short* __restrict__ ov,
    const float* __restrict__ w0, const float* __restrict__ w1,
    const float* __restrict__ w2, const float* __restrict__ w3,
    unsigned short* o0, unsigned short* o1, unsigned short* o2, unsigned short* o3,
    const int* __restrict__ mask, unsigned int* __restrict__ mb) {
  __shared__ float t[32][33];
  const int bid = blockIdx.x;
  const int tid = threadIdx.x;
  if (bid < 6144) {
    const int z = bid >> 11, vb = bid & 2047;
    const float* in = z == 0 ? q : z == 1 ? k : v;
    unsigned short* out = z == 0 ? oq : z == 1 ? ok : ov;
    const int n = B_ * S_ * D_;
    int idx = vb * 256 + tid;
#pragma unroll
    for (int i = idx * 4; i < n; i += 2048 * 256 * 4) {
      f32x4 vv = *(const f32x4*)(in + i);
      u16x4 o;
#pragma unroll
      for (int j = 0; j < 4; ++j) o[j] = f2bf(vv[j]);
      *(u16x4*)(out + i) = o;
    }
  } else if (bid < 10240) {
    const int r = bid - 6144;
    const int z = r >> 10, rr = r & 1023;
    const float* W;
    unsigned short* O;
    float sc = 1.f;
    if (z == 0) { W = w0; O = o0; sc = SCALE_; }
    else if (z == 1) { W = w1; O = o1; }
    else if (z == 2) { W = w2; O = o2; }
    else { W = w3; O = o3; }
    const int n0 = (rr & 31) * 32, k0 = (rr >> 5) * 32;
    const int tx = tid & 31, ty = tid >> 5;
    for (int i = ty; i < 32; i += 8) t[i][tx] = W[(size_t)(k0 + i) * D_ + n0 + tx];
    __syncthreads();
    for (int i = ty; i < 32; i += 8) O[(size_t)(n0 + i) * D_ + k0 + tx] = f2bf(t[tx][i] * sc);
  } else {
    const int wid = ((bid - 10240) << 2) + (tid >> 6);
    const int lane = tid & 63;
    size_t base = (size_t)wid << 6;
    unsigned long long bits = __ballot(mask[base + lane] != 0);
    if (lane == 0) *(unsigned long long*)(mb + (base >> 5)) = bits;
  }
}

// ---------------- 128x128 bf16 GEMM, B transposed (BT[n][k]), bias add ----------------
// MODE: 0 = bf16 row-major out, 1 = f32 row-major out, 2 = bf16 transposed out to [B][D][S]
template <int MODE>
__device__ __forceinline__ void gemm128(const unsigned short* __restrict__ A,
                                        const unsigned short* __restrict__ BT,
                                        const float* __restrict__ bias, float bsc,
                                        void* __restrict__ Cp, int M, int N, int K) {
  __shared__ unsigned short Al[128 * 32];
  __shared__ unsigned short Bl[128 * 32];
  const int tid = threadIdx.x;
  const int lane = tid & 63;
  const int w = tid >> 6;
  const int wr = w >> 1, wc = w & 1;
  const int wg = blockIdx.x + gridDim.x * blockIdx.y;
  const int work = (wg & 7) * 32 + (wg >> 3);
  const int nx = N >> 7;
  const int m0 = (work / nx) * 128, n0 = (work % nx) * 128;

  f32x4 acc[4][4] = {};
  const int nk = K / 32;
  const int srow = lane >> 2;
  const int scol = (lane & 3) * 8;

  const int fr = lane & 15;
  const int fc = (lane >> 4) * 8;

  for (int kt = 0; kt < nk; ++kt) {
    __syncthreads();
#pragma unroll
    for (int it = 0; it < 2; ++it) {
      int chunk = it * 4 + w;
      const unsigned short* ga = A + (size_t)(m0 + chunk * 16 + srow) * K + kt * 32 + scol;
      gload16(ga, &Al[chunk * 512]);
      const unsigned short* gb = BT + (size_t)(n0 + chunk * 16 + srow) * K + kt * 32 + scol;
      gload16(gb, &Bl[chunk * 512]);
    }
    __syncthreads();
    bf16x8 af[4], bf[4];
#pragma unroll
    for (int i = 0; i < 4; ++i)
      af[i] = __builtin_bit_cast(bf16x8, *(const u16x8*)&Al[(wr * 64 + i * 16 + fr) * 32 + fc]);
#pragma unroll
    for (int j = 0; j < 4; ++j)
      bf[j] = __builtin_bit_cast(bf16x8, *(const u16x8*)&Bl[(wc * 64 + j * 16 + fr) * 32 + fc]);
    __builtin_amdgcn_s_setprio(1);
#pragma unroll
    for (int i = 0; i < 4; ++i)
#pragma unroll
      for (int j = 0; j < 4; ++j)
        acc[i][j] = __builtin_amdgcn_mfma_f32_16x16x32_bf16(af[i], bf[j], acc[i][j], 0, 0, 0);
    __builtin_amdgcn_s_setprio(0);
  }

  const int rg = (lane >> 4) * 4;
  const int cg = lane & 15;
#pragma unroll
  for (int i = 0; i < 4; ++i)
#pragma unroll
    for (int j = 0; j < 4; ++j) {
      int col = n0 + wc * 64 + j * 16 + cg;
      float bv = bias[col] * bsc;
#pragma unroll
      for (int e = 0; e < 4; ++e) {
        int row = m0 + wr * 64 + i * 16 + rg + e;
        float v = acc[i][j][e] + bv;
        if (MODE == 1)
          ((float*)Cp)[(size_t)row * N + col] = v;
        else if (MODE == 0)
          ((unsigned short*)Cp)[(size_t)row * N + col] = f2bf(v);
        else
          ((unsigned short*)Cp)[((size_t)(row >> 11) * D_ + col) * S_ + (row & (S_ - 1))] = f2bf(v);
      }
    }
}

__global__ __launch_bounds__(256) void qkv_gemm_kernel(
    const unsigned short* __restrict__ xq, const unsigned short* __restrict__ xk,
    const unsigned short* __restrict__ xv, const unsigned short* __restrict__ wtq,
    const unsigned short* __restrict__ wtk, const unsigned short* __restrict__ wtv,
    const float* __restrict__ bq, const float* __restrict__ bk, const float* __restrict__ bv,
    unsigned short* q, unsigned short* k, unsigned short* vt) {
  if (blockIdx.z == 0)
    gemm128<0>(xq, wtq, bq, SCALE_, (void*)q, B_ * S_, D_, D_);
  else if (blockIdx.z == 1)
    gemm128<0>(xk, wtk, bk, 1.f, (void*)k, B_ * S_, D_, D_);
  else
    gemm128<2>(xv, wtv, bv, 1.f, (void*)vt, B_ * S_, D_, D_);
}

__global__ __launch_bounds__(256) void out_gemm_kernel(const unsigned short* __restrict__ x,
                                                       const unsigned short* __restrict__ wto,
                                                       const float* __restrict__ bo,
                                                       float* __restrict__ out) {
  gemm128<1>(x, wto, bo, 1.f, (void*)out, B_ * S_, D_, D_);
}

// ---------------- flash attention, swapped-QK^T 32x32, clustered phases ----------------
// Q,K bf16 [B,S,D] (Q pre-scaled by SCALE_); Vt bf16 [B,D,S]; mb bit-packed mask.
// 4 waves x 32 q-rows = 128 q/block; KVBLK=128 staged; double-buffered 64KB LDS;
// per iteration: [16 K ds_reads][stage][16 QK MFMA][16 V ds_reads][softmax][24 PV MFMA].
__global__ __launch_bounds__(256, 2) void attn_kernel(const unsigned short* __restrict__ Q,
                                                      const unsigned short* __restrict__ K,
                                                      const unsigned short* __restrict__ Vt,
                                                      const unsigned int* __restrict__ mb,
                                                      unsigned short* __restrict__ X) {
  __shared__ unsigned short Kl[2][128 * 64];     // [kv 0..127][d], XOR-swizzled 16B chunks
  __shared__ unsigned short Vl[2][2][64 * 64];   // [half][d][kv 64], XOR-swizzled

  const int tid = threadIdx.x;
  const int lane = tid & 63;
  const int w = tid >> 6;
  const int ql = lane & 31;
  const int hi = lane >> 5;

  // XCD-bijective remap: 512 blocks = 8 XCDs x 64; each XCD owns 4 consecutive bh
  const int wg = blockIdx.x + gridDim.x * blockIdx.y;
  const int swz = (wg & 7) * 64 + (wg >> 3);
  const int qt = swz & 15;
  const int bh = swz >> 4;
  const int b = bh >> 4, h = bh & 15;
  const int q_g = qt * 128 + w * 32 + ql;

  const size_t qkbase = ((size_t)b * S_) * D_ + h * DK_;
  const size_t vtbase = ((size_t)b * D_ + h * DK_) * S_;

  bf16x8 qf[4];
  {
    const unsigned short* qp = Q + qkbase + (size_t)q_g * D_ + hi * 8;
#pragma unroll
    for (int c = 0; c < 4; ++c)
      qf[c] = __builtin_bit_cast(bf16x8, *(const u16x8*)(qp + c * 16));
  }

  const int lr = lane >> 3;
  const int seg = (lane & 7) ^ lr;
  const unsigned short* Ks = K + qkbase + (size_t)(w * 32 + lr) * D_ + seg * 8;
  const unsigned short* Vs = Vt + vtbase + (size_t)(w * 16 + lr) * S_ + seg * 8;

  auto stage = [&](int kt, int bufi) {  // kt indexes 128-row KV tiles
#pragma unroll
    for (int c = 0; c < 4; ++c)
      gload16(Ks + ((size_t)kt * 128 + c * 8) * D_, &Kl[bufi][(w * 32 + c * 8) * 64]);
#pragma unroll
    for (int c = 0; c < 4; ++c)
      gload16(Vs + (size_t)((c & 1) * 8) * S_ + kt * 128 + (c >> 1) * 64,
              &Vl[bufi][c >> 1][(w * 16 + (c & 1) * 8) * 64]);
  };

  const unsigned long long* mrow =
      (const unsigned long long*)mb + ((size_t)b * S_ + q_g) * 32;

  f32x16 o0 = {}, o1 = {};  // O^T accumulators, d-tiles 0 (d 0..31) and 1 (d 32..63)
  f32x16 o2 = {};           // ones-MFMA accumulator: every row = sum_k P (lsum)
  const int sw = (ql & 7) << 4;

  const unsigned int one2 = 0x3F803F80u;  // two bf16 1.0
  const bf16x8 onesf = __builtin_bit_cast(bf16x8, u32x4{one2, one2, one2, one2});

  stage(0, 0);
  const int NT = S_ / 128;

  for (int kt = 0; kt < NT; ++kt) {
    const int buf = kt & 1;
    __syncthreads();                  // drains stage(kt); prior reads of buf^1 done
    unsigned long long M0 = mrow[kt * 2], M1 = mrow[kt * 2 + 1];

    // ---- phase 1: ALL K-fragment ds_reads (latency paid once, pipelined) ----
    bf16x8 kf[2][2][4];  // [half][subtile][c]
#pragma unroll
    for (int hh = 0; hh < 2; ++hh) {
      const char* Kb = (const char*)&Kl[buf][hh * 64 * 64];
#pragma unroll
      for (int r = 0; r < 2; ++r)
#pragma unroll
        for (int c = 0; c < 4; ++c)
          kf[hh][r][c] = __builtin_bit_cast(
              bf16x8, *(const u16x8*)(Kb + (((r * 32 + ql) * 128 + c * 32 + hi * 16) ^ sw)));
    }
    if (kt < NT - 1) stage(kt + 1, buf ^ 1);

    // ---- phase 2: QK^T MFMA cluster (16) ----
    f32x16 s[2][2] = {};  // [half][subtile]
    __builtin_amdgcn_s_setprio(1);
#pragma unroll
    for (int hh = 0; hh < 2; ++hh)
#pragma unroll
      for (int c = 0; c < 4; ++c) {
        s[hh][0] = __builtin_amdgcn_mfma_f32_32x32x16_bf16(kf[hh][0][c], qf[c], s[hh][0], 0, 0, 0);
        s[hh][1] = __builtin_amdgcn_mfma_f32_32x32x16_bf16(kf[hh][1][c], qf[c], s[hh][1], 0, 0, 0);
      }
    __builtin_amdgcn_s_setprio(0);

    // ---- phase 3: ALL V-fragment ds_reads (latency hides under softmax VALU) ----
    bf16x8 vf[2][2][4];  // [half][d-subtile][kc]
#pragma unroll
    for (int hh = 0; hh < 2; ++hh) {
      const char* Vb = (const char*)&Vl[buf][hh][0];
#pragma unroll
      for (int nt = 0; nt < 2; ++nt)
#pragma unroll
        for (int kc = 0; kc < 4; ++kc)
          vf[hh][nt][kc] = __builtin_bit_cast(
              bf16x8, *(const u16x8*)(Vb + (((nt * 32 + ql) * 128 + kc * 32 + hi * 16) ^ sw)));
    }

    // ---- phase 4: softmax + pack per half ----
    u32x4 pw[2][4];
#pragma unroll
    for (int hh = 0; hh < 2; ++hh) {
      const unsigned long long M = hh ? M1 : M0;
      unsigned int W0 = (unsigned int)(M >> (hi * 4));
      unsigned int W1 = (unsigned int)(M >> (32 + hi * 4));
#pragma unroll
      for (int r = 0; r < 16; ++r) {
        const int krl = (r & 3) + 8 * (r >> 2);
        unsigned int mk0 = bit_mask(W0, krl);
        float p0 = exp2v(s[hh][0][r]);
        s[hh][0][r] = __builtin_bit_cast(float, __builtin_bit_cast(unsigned int, p0) & mk0);
        unsigned int mk1 = bit_mask(W1, krl);
        float p1 = exp2v(s[hh][1][r]);
        s[hh][1][r] = __builtin_bit_cast(float, __builtin_bit_cast(unsigned int, p1) & mk1);
      }
#pragma unroll
      for (int kc = 0; kc < 4; ++kc) {
        const int rb = (kc & 1) * 8;
        const int st = kc >> 1;
        unsigned int w0 = cvtpk(s[hh][st][rb + 0], s[hh][st][rb + 1]);
        unsigned int w1 = cvtpk(s[hh][st][rb + 2], s[hh][st][rb + 3]);
        unsigned int w2 = cvtpk(s[hh][st][rb + 4], s[hh][st][rb + 5]);
        unsigned int w3 = cvtpk(s[hh][st][rb + 6], s[hh][st][rb + 7]);
        unsigned int u0, u1, u2, u3;
#if __has_builtin(__builtin_amdgcn_permlane32_swap)
        { auto r02 = __builtin_amdgcn_permlane32_swap(w0, w2, false, false);
          u0 = r02[0]; u2 = r02[1]; }
        { auto r13 = __builtin_amdgcn_permlane32_swap(w1, w3, false, false);
          u1 = r13[0]; u3 = r13[1]; }
#else
        { unsigned int t0 = (unsigned int)__shfl_xor((int)w0, 32);
          unsigned int t2 = (unsigned int)__shfl_xor((int)w2, 32);
          u0 = hi ? t2 : w0; u2 = hi ? w2 : t0;
          unsigned int t1 = (unsigned int)__shfl_xor((int)w1, 32);
          unsigned int t3 = (unsigned int)__shfl_xor((int)w3, 32);
          u1 = hi ? t3 : w1; u3 = hi ? w3 : t1; }
#endif
        pw[hh][kc] = u32x4{u0, u1, u2, u3};
      }
    }

    // ---- phase 5: PV MFMA cluster (24) ----
    __builtin_amdgcn_s_setprio(1);
#pragma unroll
    for (int hh = 0; hh < 2; ++hh)
#pragma unroll
      for (int kc = 0; kc < 4; ++kc) {
        bf16x8 pf = __builtin_bit_cast(bf16x8, pw[hh][kc]);
        o0 = __builtin_amdgcn_mfma_f32_32x32x16_bf16(vf[hh][0][kc], pf, o0, 0, 0, 0);
        o1 = __builtin_amdgcn_mfma_f32_32x32x16_bf16(vf[hh][1][kc], pf, o1, 0, 0, 0);
        o2 = __builtin_amdgcn_mfma_f32_32x32x16_bf16(onesf, pf, o2, 0, 0, 0);
      }
    __builtin_amdgcn_s_setprio(0);
  }

  // ---- epilogue: normalize (lsum = o2[0], identical in all lanes of col ql) ----
  float inv = 1.f / o2[0];
  unsigned short* Xp = X + ((size_t)b * S_ + q_g) * D_ + h * DK_;
#pragma unroll
  for (int rb = 0; rb < 4; ++rb) {
    int d0 = 8 * rb + 4 * hi;
    *(unsigned int*)(Xp + d0) = cvtpk(o0[4 * rb + 0] * inv, o0[4 * rb + 1] * inv);
    *(unsigned int*)(Xp + d0 + 2) = cvtpk(o0[4 * rb + 2] * inv, o0[4 * rb + 3] * inv);
    *(unsigned int*)(Xp + 32 + d0) = cvtpk(o1[4 * rb + 0] * inv, o1[4 * rb + 1] * inv);
    *(unsigned int*)(Xp + 32 + d0 + 2) = cvtpk(o1[4 * rb + 2] * inv, o1[4 * rb + 3] * inv);
  }
}

extern "C" void kernel_launch(void* const* d_in, const int* in_sizes, int n_in,
                              void* d_out, int out_size, void* d_ws, size_t ws_size,
                              hipStream_t stream) {
  const float* query = (const float*)d_in[0];
  const float* key = (const float*)d_in[1];
  const float* value = (const float*)d_in[2];
  const int* mask = (const int*)d_in[3];
  const float* Wq = (const float*)d_in[4];
  const float* bq = (const float*)d_in[5];
  const float* Wk = (const float*)d_in[6];
  const float* bk = (const float*)d_in[7];
  const float* Wv = (const float*)d_in[8];
  const float* bv = (const float*)d_in[9];
  const float* Wo = (const float*)d_in[10];
  const float* bo = (const float*)d_in[11];
  float* out = (float*)d_out;

  const size_t ACT = (size_t)B_ * S_ * D_;  // 4,194,304
  const size_t WSZ = (size_t)D_ * D_;
  unsigned short* ws = (unsigned short*)d_ws;
  unsigned short* xq = ws;                 // also reused as xb (attn out) after qkv_gemm
  unsigned short* xk = xq + ACT;
  unsigned short* xv = xk + ACT;
  unsigned short* wtq = xv + ACT;
  unsigned short* wtk = wtq + WSZ;
  unsigned short* wtv = wtk + WSZ;
  unsigned short* wto = wtv + WSZ;
  unsigned short* qb = wto + WSZ;
  unsigned short* kb = qb + ACT;
  unsigned short* vt = kb + ACT;
  unsigned int* mbp = (unsigned int*)(vt + ACT);  // 1MB bit-packed mask
  unsigned short* xb = xq;                        // alias: xq dead after qkv_gemm

  prep_kernel<<<43008, 256, 0, stream>>>(query, key, value, xq, xk, xv,
                                         Wq, Wk, Wv, Wo, wtq, wtk, wtv, wto,
                                         mask, mbp);

  dim3 gg(8, 32, 3);
  qkv_gemm_kernel<<<gg, 256, 0, stream>>>(xq, xk, xv, wtq, wtk, wtv, bq, bk, bv, qb, kb, vt);

  dim3 ag(S_ / 128, B_ * H_);
  attn_kernel<<<ag, 256, 0, stream>>>(qb, kb, vt, mbp, xb);

  dim3 og(8, 32, 1);
  out_gemm_kernel<<<og, 256, 0, stream>>>(xb, wto, bo, out);
}

// Round 8
// 153.740 us; speedup vs baseline: 1.6751x; 1.0639x over previous
//
#include <hip/hip_runtime.h>
#include <cstdint>

#define B_ 2
#define S_ 2048
#define D_ 1024
#define H_ 16
#define DK_ 64
// 0.125 (1/sqrt(DK)) * log2(e): folded into Wq/bq so softmax uses exp2 directly
#define SCALE_ 0.18033688011112042f

typedef float f32x4 __attribute__((ext_vector_type(4)));
typedef float f32x16 __attribute__((ext_vector_type(16)));
typedef __bf16 bf16x8 __attribute__((ext_vector_type(8)));
typedef unsigned short u16x8 __attribute__((ext_vector_type(8)));
typedef unsigned short u16x4 __attribute__((ext_vector_type(4)));
typedef unsigned int u32x4 __attribute__((ext_vector_type(4)));

__device__ __forceinline__ unsigned short f2bf(float x) {
  unsigned int u = __builtin_bit_cast(unsigned int, x);
  u += 0x7FFFu + ((u >> 16) & 1u);   // round-to-nearest-even
  return (unsigned short)(u >> 16);
}

__device__ __forceinline__ void gload16(const void* g, void* l) {
  __builtin_amdgcn_global_load_lds((__attribute__((address_space(1))) void*)(void*)g,
                                   (__attribute__((address_space(3))) void*)l, 16, 0, 0);
}

__device__ __forceinline__ float exp2v(float x) {
  float r;
  asm("v_exp_f32 %0, %1" : "=v"(r) : "v"(x));
  return r;
}

__device__ __forceinline__ unsigned int cvtpk(float a, float b) {
  unsigned int r;
  asm("v_cvt_pk_bf16_f32 %0, %1, %2" : "=v"(r) : "v"(a), "v"(b));
  return r;
}

// sign-extended 1-bit field: 0 or 0xFFFFFFFF
__device__ __forceinline__ unsigned int bit_mask(unsigned int w, int bit) {
#if __has_builtin(__builtin_amdgcn_sbfe)
  return (unsigned int)__builtin_amdgcn_sbfe((int)w, bit, 1);
#else
  return (unsigned int)((int)(w << (31 - bit)) >> 31);
#endif
}

// ---------------- fused prep: cvt3 | wtrans | maskpack ----------------
__global__ __launch_bounds__(256) void prep_kernel(
    const float* __restrict__ q, const float* __restrict__ k, const float* __restrict__ v,
    unsigned short* __restrict__ oq, unsigned short* __restrict__ ok,
    unsigned short* __restrict__ ov,
    const float* __restrict__ w0, const float* __restrict__ w1,
    const float* __restrict__ w2, const float* __restrict__ w3,
    unsigned short* o0, unsigned short* o1, unsigned short* o2, unsigned short* o3,
    const int* __restrict__ mask, unsigned int* __restrict__ mb) {
  __shared__ float t[32][33];
  const int bid = blockIdx.x;
  const int tid = threadIdx.x;
  if (bid < 6144) {
    const int z = bid >> 11, vb = bid & 2047;
    const float* in = z == 0 ? q : z == 1 ? k : v;
    unsigned short* out = z == 0 ? oq : z == 1 ? ok : ov;
    const int n = B_ * S_ * D_;
    int idx = vb * 256 + tid;
#pragma unroll
    for (int i = idx * 4; i < n; i += 2048 * 256 * 4) {
      f32x4 vv = *(const f32x4*)(in + i);
      u16x4 o;
#pragma unroll
      for (int j = 0; j < 4; ++j) o[j] = f2bf(vv[j]);
      *(u16x4*)(out + i) = o;
    }
  } else if (bid < 10240) {
    const int r = bid - 6144;
    const int z = r >> 10, rr = r & 1023;
    const float* W;
    unsigned short* O;
    float sc = 1.f;
    if (z == 0) { W = w0; O = o0; sc = SCALE_; }
    else if (z == 1) { W = w1; O = o1; }
    else if (z == 2) { W = w2; O = o2; }
    else { W = w3; O = o3; }
    const int n0 = (rr & 31) * 32, k0 = (rr >> 5) * 32;
    const int tx = tid & 31, ty = tid >> 5;
    for (int i = ty; i < 32; i += 8) t[i][tx] = W[(size_t)(k0 + i) * D_ + n0 + tx];
    __syncthreads();
    for (int i = ty; i < 32; i += 8) O[(size_t)(n0 + i) * D_ + k0 + tx] = f2bf(t[tx][i] * sc);
  } else {
    const int wid = ((bid - 10240) << 2) + (tid >> 6);
    const int lane = tid & 63;
    size_t base = (size_t)wid << 6;
    unsigned long long bits = __ballot(mask[base + lane] != 0);
    if (lane == 0) *(unsigned long long*)(mb + (base >> 5)) = bits;
  }
}

// ---------------- 128xTN bf16 GEMM, B transposed (BT[n][k]), bias add ----------------
// MODE: 0 = bf16 row-major out, 1 = f32 row-major out, 2 = bf16 transposed out to [B][D][S]
// TN: tile N (128 or 64). NWN: waves along N (NWM = 4/NWN).
// Double-buffered LDS pipeline (1 barrier/K-step) + seg-XOR swizzle (conflict-free reads).
template <int MODE, int TN, int NWN>
__device__ __forceinline__ void gemm_t(const unsigned short* __restrict__ A,
                                       const unsigned short* __restrict__ BT,
                                       const float* __restrict__ bias, float bsc,
                                       void* __restrict__ Cp, int M, int N, int K) {
  constexpr int NWM = 4 / NWN;
  constexpr int WM = 128 / NWM;   // rows per wave
  constexpr int WN = TN / NWN;    // cols per wave
  constexpr int MR = WM / 16, NR = WN / 16;
  __shared__ unsigned short Al[2][128 * 32];
  __shared__ unsigned short Bl[2][TN * 32];
  const int tid = threadIdx.x;
  const int lane = tid & 63;
  const int w = tid >> 6;
  const int wr = w / NWN, wc = w % NWN;
  // XCD-chunked bijective remap (nwg must be a multiple of 8)
  const int nwg = gridDim.x * gridDim.y;
  const int wg = blockIdx.x + gridDim.x * blockIdx.y;
  const int work = (wg & 7) * (nwg >> 3) + (wg >> 3);
  const int nx = N / TN;
  const int m0 = (work / nx) * 128, n0 = (work % nx) * TN;

  f32x4 acc[MR][NR] = {};
  const int nk = K / 32;
  const int srow = lane >> 2;                              // staging row within 16-row chunk
  const int scol = ((lane & 3) ^ ((lane >> 3) & 3)) * 8;   // pre-swizzled source seg

  const int fr = lane & 15;
  const int rsw = ((lane >> 4) ^ ((fr >> 1) & 3)) * 8;     // read seg (swizzled), ushorts

  auto stage = [&](int kt, int bufi) {
#pragma unroll
    for (int it = 0; it < 2; ++it) {
      int chunk = it * 4 + w;
      gload16(A + (size_t)(m0 + chunk * 16 + srow) * K + kt * 32 + scol,
              &Al[bufi][chunk * 512]);
    }
#pragma unroll
    for (int it = 0; it < TN / 64; ++it) {
      int chunk = it * 4 + w;
      gload16(BT + (size_t)(n0 + chunk * 16 + srow) * K + kt * 32 + scol,
              &Bl[bufi][chunk * 512]);
    }
  };

  stage(0, 0);
  for (int kt = 0; kt < nk; ++kt) {
    const int buf = kt & 1;
    __syncthreads();                   // drains stage(kt); prior reads of buf done
    if (kt + 1 < nk) stage(kt + 1, buf ^ 1);
    bf16x8 af[MR], bf[NR];
#pragma unroll
    for (int i = 0; i < MR; ++i)
      af[i] = __builtin_bit_cast(bf16x8,
          *(const u16x8*)&Al[buf][(wr * WM + i * 16 + fr) * 32 + rsw]);
#pragma unroll
    for (int j = 0; j < NR; ++j)
      bf[j] = __builtin_bit_cast(bf16x8,
          *(const u16x8*)&Bl[buf][(wc * WN + j * 16 + fr) * 32 + rsw]);
    __builtin_amdgcn_s_setprio(1);
#pragma unroll
    for (int i = 0; i < MR; ++i)
#pragma unroll
      for (int j = 0; j < NR; ++j)
        acc[i][j] = __builtin_amdgcn_mfma_f32_16x16x32_bf16(af[i], bf[j], acc[i][j], 0, 0, 0);
    __builtin_amdgcn_s_setprio(0);
  }

  const int rg = (lane >> 4) * 4;
  const int cg = lane & 15;
#pragma unroll
  for (int i = 0; i < MR; ++i)
#pragma unroll
    for (int j = 0; j < NR; ++j) {
      int col = n0 + wc * WN + j * 16 + cg;
      float bv = bias[col] * bsc;
#pragma unroll
      for (int e = 0; e < 4; ++e) {
        int row = m0 + wr * WM + i * 16 + rg + e;
        float v = acc[i][j][e] + bv;
        if (MODE == 1)
          ((float*)Cp)[(size_t)row * N + col] = v;
        else if (MODE == 0)
          ((unsigned short*)Cp)[(size_t)row * N + col] = f2bf(v);
        else
          ((unsigned short*)Cp)[((size_t)(row >> 11) * D_ + col) * S_ + (row & (S_ - 1))] = f2bf(v);
      }
    }
}

__global__ __launch_bounds__(256) void qkv_gemm_kernel(
    const unsigned short* __restrict__ xq, const unsigned short* __restrict__ xk,
    const unsigned short* __restrict__ xv, const unsigned short* __restrict__ wtq,
    const unsigned short* __restrict__ wtk, const unsigned short* __restrict__ wtv,
    const float* __restrict__ bq, const float* __restrict__ bk, const float* __restrict__ bv,
    unsigned short* q, unsigned short* k, unsigned short* vt) {
  if (blockIdx.z == 0)
    gemm_t<0, 128, 2>(xq, wtq, bq, SCALE_, (void*)q, B_ * S_, D_, D_);
  else if (blockIdx.z == 1)
    gemm_t<0, 128, 2>(xk, wtk, bk, 1.f, (void*)k, B_ * S_, D_, D_);
  else
    gemm_t<2, 128, 2>(xv, wtv, bv, 1.f, (void*)vt, B_ * S_, D_, D_);
}

__global__ __launch_bounds__(256) void out_gemm_kernel(const unsigned short* __restrict__ x,
                                                       const unsigned short* __restrict__ wto,
                                                       const float* __restrict__ bo,
                                                       float* __restrict__ out) {
  gemm_t<1, 64, 1>(x, wto, bo, 1.f, (void*)out, B_ * S_, D_, D_);
}

// ---------------- flash attention, swapped-QK^T 32x32, clustered phases ----------------
// Q,K bf16 [B,S,D] (Q pre-scaled by SCALE_); Vt bf16 [B,D,S]; mb bit-packed mask.
// 4 waves x 32 q-rows = 128 q/block; KVBLK=128 staged; double-buffered 64KB LDS;
// per iteration: [16 K ds_reads][stage][16 QK MFMA][16 V ds_reads][softmax][24 PV MFMA].
__global__ __launch_bounds__(256, 2) void attn_kernel(const unsigned short* __restrict__ Q,
                                                      const unsigned short* __restrict__ K,
                                                      const unsigned short* __restrict__ Vt,
                                                      const unsigned int* __restrict__ mb,
                                                      unsigned short* __restrict__ X) {
  __shared__ unsigned short Kl[2][128 * 64];     // [kv 0..127][d], XOR-swizzled 16B chunks
  __shared__ unsigned short Vl[2][2][64 * 64];   // [half][d][kv 64], XOR-swizzled

  const int tid = threadIdx.x;
  const int lane = tid & 63;
  const int w = tid >> 6;
  const int ql = lane & 31;
  const int hi = lane >> 5;

  // XCD-bijective remap: 512 blocks = 8 XCDs x 64; each XCD owns 4 consecutive bh
  const int wg = blockIdx.x + gridDim.x * blockIdx.y;
  const int swz = (wg & 7) * 64 + (wg >> 3);
  const int qt = swz & 15;
  const int bh = swz >> 4;
  const int b = bh >> 4, h = bh & 15;
  const int q_g = qt * 128 + w * 32 + ql;

  const size_t qkbase = ((size_t)b * S_) * D_ + h * DK_;
  const size_t vtbase = ((size_t)b * D_ + h * DK_) * S_;

  bf16x8 qf[4];
  {
    const unsigned short* qp = Q + qkbase + (size_t)q_g * D_ + hi * 8;
#pragma unroll
    for (int c = 0; c < 4; ++c)
      qf[c] = __builtin_bit_cast(bf16x8, *(const u16x8*)(qp + c * 16));
  }

  const int lr = lane >> 3;
  const int seg = (lane & 7) ^ lr;
  const unsigned short* Ks = K + qkbase + (size_t)(w * 32 + lr) * D_ + seg * 8;
  const unsigned short* Vs = Vt + vtbase + (size_t)(w * 16 + lr) * S_ + seg * 8;

  auto stage = [&](int kt, int bufi) {  // kt indexes 128-row KV tiles
#pragma unroll
    for (int c = 0; c < 4; ++c)
      gload16(Ks + ((size_t)kt * 128 + c * 8) * D_, &Kl[bufi][(w * 32 + c * 8) * 64]);
#pragma unroll
    for (int c = 0; c < 4; ++c)
      gload16(Vs + (size_t)((c & 1) * 8) * S_ + kt * 128 + (c >> 1) * 64,
              &Vl[bufi][c >> 1][(w * 16 + (c & 1) * 8) * 64]);
  };

  const unsigned long long* mrow =
      (const unsigned long long*)mb + ((size_t)b * S_ + q_g) * 32;

  f32x16 o0 = {}, o1 = {};  // O^T accumulators, d-tiles 0 (d 0..31) and 1 (d 32..63)
  f32x16 o2 = {};           // ones-MFMA accumulator: every row = sum_k P (lsum)
  const int sw = (ql & 7) << 4;

  const unsigned int one2 = 0x3F803F80u;  // two bf16 1.0
  const bf16x8 onesf = __builtin_bit_cast(bf16x8, u32x4{one2, one2, one2, one2});

  stage(0, 0);
  const int NT = S_ / 128;

  for (int kt = 0; kt < NT; ++kt) {
    const int buf = kt & 1;
    __syncthreads();                  // drains stage(kt); prior reads of buf^1 done
    unsigned long long M0 = mrow[kt * 2], M1 = mrow[kt * 2 + 1];

    // ---- phase 1: ALL K-fragment ds_reads (latency paid once, pipelined) ----
    bf16x8 kf[2][2][4];  // [half][subtile][c]
#pragma unroll
    for (int hh = 0; hh < 2; ++hh) {
      const char* Kb = (const char*)&Kl[buf][hh * 64 * 64];
#pragma unroll
      for (int r = 0; r < 2; ++r)
#pragma unroll
        for (int c = 0; c < 4; ++c)
          kf[hh][r][c] = __builtin_bit_cast(
              bf16x8, *(const u16x8*)(Kb + (((r * 32 + ql) * 128 + c * 32 + hi * 16) ^ sw)));
    }
    if (kt < NT - 1) stage(kt + 1, buf ^ 1);

    // ---- phase 2: QK^T MFMA cluster (16) ----
    f32x16 s[2][2] = {};  // [half][subtile]
    __builtin_amdgcn_s_setprio(1);
#pragma unroll
    for (int hh = 0; hh < 2; ++hh)
#pragma unroll
      for (int c = 0; c < 4; ++c) {
        s[hh][0] = __builtin_amdgcn_mfma_f32_32x32x16_bf16(kf[hh][0][c], qf[c], s[hh][0], 0, 0, 0);
        s[hh][1] = __builtin_amdgcn_mfma_f32_32x32x16_bf16(kf[hh][1][c], qf[c], s[hh][1], 0, 0, 0);
      }
    __builtin_amdgcn_s_setprio(0);

    // ---- phase 3: ALL V-fragment ds_reads (latency hides under softmax VALU) ----
    bf16x8 vf[2][2][4];  // [half][d-subtile][kc]
#pragma unroll
    for (int hh = 0; hh < 2; ++hh) {
      const char* Vb = (const char*)&Vl[buf][hh][0];
#pragma unroll
      for (int nt = 0; nt < 2; ++nt)
#pragma unroll
        for (int kc = 0; kc < 4; ++kc)
          vf[hh][nt][kc] = __builtin_bit_cast(
              bf16x8, *(const u16x8*)(Vb + (((nt * 32 + ql) * 128 + kc * 32 + hi * 16) ^ sw)));
    }

    // ---- phase 4: softmax + pack per half ----
    u32x4 pw[2][4];
#pragma unroll
    for (int hh = 0; hh < 2; ++hh) {
      const unsigned long long M = hh ? M1 : M0;
      unsigned int W0 = (unsigned int)(M >> (hi * 4));
      unsigned int W1 = (unsigned int)(M >> (32 + hi * 4));
#pragma unroll
      for (int r = 0; r < 16; ++r) {
        const int krl = (r & 3) + 8 * (r >> 2);
        unsigned int mk0 = bit_mask(W0, krl);
        float p0 = exp2v(s[hh][0][r]);
        s[hh][0][r] = __builtin_bit_cast(float, __builtin_bit_cast(unsigned int, p0) & mk0);
        unsigned int mk1 = bit_mask(W1, krl);
        float p1 = exp2v(s[hh][1][r]);
        s[hh][1][r] = __builtin_bit_cast(float, __builtin_bit_cast(unsigned int, p1) & mk1);
      }
#pragma unroll
      for (int kc = 0; kc < 4; ++kc) {
        const int rb = (kc & 1) * 8;
        const int st = kc >> 1;
        unsigned int w0 = cvtpk(s[hh][st][rb + 0], s[hh][st][rb + 1]);
        unsigned int w1 = cvtpk(s[hh][st][rb + 2], s[hh][st][rb + 3]);
        unsigned int w2 = cvtpk(s[hh][st][rb + 4], s[hh][st][rb + 5]);
        unsigned int w3 = cvtpk(s[hh][st][rb + 6], s[hh][st][rb + 7]);
        unsigned int u0, u1, u2, u3;
#if __has_builtin(__builtin_amdgcn_permlane32_swap)
        { auto r02 = __builtin_amdgcn_permlane32_swap(w0, w2, false, false);
          u0 = r02[0]; u2 = r02[1]; }
        { auto r13 = __builtin_amdgcn_permlane32_swap(w1, w3, false, false);
          u1 = r13[0]; u3 = r13[1]; }
#else
        { unsigned int t0 = (unsigned int)__shfl_xor((int)w0, 32);
          unsigned int t2 = (unsigned int)__shfl_xor((int)w2, 32);
          u0 = hi ? t2 : w0; u2 = hi ? w2 : t0;
          unsigned int t1 = (unsigned int)__shfl_xor((int)w1, 32);
          unsigned int t3 = (unsigned int)__shfl_xor((int)w3, 32);
          u1 = hi ? t3 : w1; u3 = hi ? w3 : t1; }
#endif
        pw[hh][kc] = u32x4{u0, u1, u2, u3};
      }
    }

    // ---- phase 5: PV MFMA cluster (24) ----
    __builtin_amdgcn_s_setprio(1);
#pragma unroll
    for (int hh = 0; hh < 2; ++hh)
#pragma unroll
      for (int kc = 0; kc < 4; ++kc) {
        bf16x8 pf = __builtin_bit_cast(bf16x8, pw[hh][kc]);
        o0 = __builtin_amdgcn_mfma_f32_32x32x16_bf16(vf[hh][0][kc], pf, o0, 0, 0, 0);
        o1 = __builtin_amdgcn_mfma_f32_32x32x16_bf16(vf[hh][1][kc], pf, o1, 0, 0, 0);
        o2 = __builtin_amdgcn_mfma_f32_32x32x16_bf16(onesf, pf, o2, 0, 0, 0);
      }
    __builtin_amdgcn_s_setprio(0);
  }

  // ---- epilogue: normalize (lsum = o2[0], identical in all lanes of col ql) ----
  float inv = 1.f / o2[0];
  unsigned short* Xp = X + ((size_t)b * S_ + q_g) * D_ + h * DK_;
#pragma unroll
  for (int rb = 0; rb < 4; ++rb) {
    int d0 = 8 * rb + 4 * hi;
    *(unsigned int*)(Xp + d0) = cvtpk(o0[4 * rb + 0] * inv, o0[4 * rb + 1] * inv);
    *(unsigned int*)(Xp + d0 + 2) = cvtpk(o0[4 * rb + 2] * inv, o0[4 * rb + 3] * inv);
    *(unsigned int*)(Xp + 32 + d0) = cvtpk(o1[4 * rb + 0] * inv, o1[4 * rb + 1] * inv);
    *(unsigned int*)(Xp + 32 + d0 + 2) = cvtpk(o1[4 * rb + 2] * inv, o1[4 * rb + 3] * inv);
  }
}

extern "C" void kernel_launch(void* const* d_in, const int* in_sizes, int n_in,
                              void* d_out, int out_size, void* d_ws, size_t ws_size,
                              hipStream_t stream) {
  const float* query = (const float*)d_in[0];
  const float* key = (const float*)d_in[1];
  const float* value = (const float*)d_in[2];
  const int* mask = (const int*)d_in[3];
  const float* Wq = (const float*)d_in[4];
  const float* bq = (const float*)d_in[5];
  const float* Wk = (const float*)d_in[6];
  const float* bk = (const float*)d_in[7];
  const float* Wv = (const float*)d_in[8];
  const float* bv = (const float*)d_in[9];
  const float* Wo = (const float*)d_in[10];
  const float* bo = (const float*)d_in[11];
  float* out = (float*)d_out;

  const size_t ACT = (size_t)B_ * S_ * D_;  // 4,194,304
  const size_t WSZ = (size_t)D_ * D_;
  unsigned short* ws = (unsigned short*)d_ws;
  unsigned short* xq = ws;                 // also reused as xb (attn out) after qkv_gemm
  unsigned short* xk = xq + ACT;
  unsigned short* xv = xk + ACT;
  unsigned short* wtq = xv + ACT;
  unsigned short* wtk = wtq + WSZ;
  unsigned short* wtv = wtk + WSZ;
  unsigned short* wto = wtv + WSZ;
  unsigned short* qb = wto + WSZ;
  unsigned short* kb = qb + ACT;
  unsigned short* vt = kb + ACT;
  unsigned int* mbp = (unsigned int*)(vt + ACT);  // 1MB bit-packed mask
  unsigned short* xb = xq;                        // alias: xq dead after qkv_gemm

  prep_kernel<<<43008, 256, 0, stream>>>(query, key, value, xq, xk, xv,
                                         Wq, Wk, Wv, Wo, wtq, wtk, wtv, wto,
                                         mask, mbp);

  dim3 gg(8, 32, 3);
  qkv_gemm_kernel<<<gg, 256, 0, stream>>>(xq, xk, xv, wtq, wtk, wtv, bq, bk, bv, qb, kb, vt);

  dim3 ag(S_ / 128, B_ * H_);
  attn_kernel<<<ag, 256, 0, stream>>>(qb, kb, vt, mbp, xb);

  dim3 og(16, 32, 1);
  out_gemm_kernel<<<og, 256, 0, stream>>>(xb, wto, bo, out);
}